// Round 1
// baseline (456.001 us; speedup 1.0000x reference)
//
#include <hip/hip_runtime.h>

typedef unsigned short u16;
typedef __attribute__((ext_vector_type(8))) short short8;
typedef __attribute__((ext_vector_type(4))) float f32x4;

#define EPSV 1e-5f

__device__ __forceinline__ u16 f2bf(float f) {
    unsigned u = __float_as_uint(f);
    u += 0x7fffu + ((u >> 16) & 1u);
    return (u16)(u >> 16);
}

__device__ __forceinline__ f32x4 mfma_bf16(short8 a, short8 b, f32x4 c) {
    return __builtin_amdgcn_mfma_f32_16x16x32_bf16(a, b, c, 0, 0, 0);
}

__device__ __forceinline__ void gload_lds16(const void* g, void* l) {
    __builtin_amdgcn_global_load_lds((const __attribute__((address_space(1))) void*)g,
                                     (__attribute__((address_space(3))) void*)l, 16, 0, 0);
}

// ---------------------------------------------------------------------------
// Kernel 1: fused QKV 1x1-conv + bias + PReLU + per-head LayerNorm + affine.
// One block per (b,t). Conv done as 96x64 @ 64x64 bf16 MFMA GEMM.
// Q/K written as bf16 [n=h*8+b][t][d=o*64+f] (d=256); V as [n][t][d=o*64+f] (d=1024).
// ---------------------------------------------------------------------------
__global__ __launch_bounds__(256) void k_qkv(
    const float* __restrict__ x,
    const float* __restrict__ qw, const float* __restrict__ qb, const float* __restrict__ qa,
    const float* __restrict__ qg, const float* __restrict__ qbt,
    const float* __restrict__ kw, const float* __restrict__ kb, const float* __restrict__ ka,
    const float* __restrict__ kg, const float* __restrict__ kbt,
    const float* __restrict__ vw, const float* __restrict__ vb, const float* __restrict__ va,
    const float* __restrict__ vg, const float* __restrict__ vbt,
    u16* __restrict__ Qb, u16* __restrict__ Kb, u16* __restrict__ Vb)
{
    __shared__ u16 xT[64][72];     // [f][c] bf16 (transposed x slice)
    __shared__ u16 wsb[96][72];    // [och][c] bf16 (rows 0-15 Q, 16-31 K, 32-95 V)
    __shared__ float ys[96][64];   // PReLU'd conv output [och][f]
    __shared__ float bias_s[96], slope_s[96];

    const int tid = threadIdx.x, w = tid >> 6, lane = tid & 63;
    const int b = blockIdx.x >> 10, t = blockIdx.x & 1023;

    // stage weights (fp32 -> bf16)
#pragma unroll
    for (int i = 0; i < 24; i++) {
        int idx = tid + i * 256;           // 0..6143
        int row = idx >> 6, c = idx & 63;
        float wv = (row < 16) ? qw[idx] : ((row < 32) ? kw[idx - 1024] : vw[idx - 2048]);
        wsb[row][c] = f2bf(wv);
    }
    if (tid < 96) {
        int row = tid; float bv, sv;
        if (row < 16)      { bv = qb[row];      sv = qa[row >> 2]; }
        else if (row < 32) { bv = kb[row - 16]; sv = ka[(row - 16) >> 2]; }
        else               { bv = vb[row - 32]; sv = va[(row - 32) >> 4]; }
        bias_s[row] = bv; slope_s[row] = sv;
    }
    // stage x[b,:,t,:] transposed -> xT[f][c]
    const float* xbt = x + ((size_t)(b * 64) * 1024 + t) * 64;
#pragma unroll
    for (int k = 0; k < 4; k++) {
        int chunk = tid + k * 256;        // 0..1023  (64 c-rows x 16 float4)
        int c = chunk >> 4, q = chunk & 15;
        float4 v = *(const float4*)(xbt + (size_t)c * 65536 + q * 4);
        xT[q * 4 + 0][c] = f2bf(v.x);
        xT[q * 4 + 1][c] = f2bf(v.y);
        xT[q * 4 + 2][c] = f2bf(v.z);
        xT[q * 4 + 3][c] = f2bf(v.w);
    }
    __syncthreads();

    // conv: y[o][f] = sum_c w[o][c] x[c][f] ; 6x4 tiles of 16x16, K=64
#pragma unroll
    for (int i = 0; i < 6; i++) {
        int tile = w * 6 + i;
        int mt = tile >> 2, nt = tile & 3;
        f32x4 acc = {0.f, 0.f, 0.f, 0.f};
#pragma unroll
        for (int kt = 0; kt < 2; kt++) {
            short8 a  = *(const short8*)(&wsb[mt * 16 + (lane & 15)][kt * 32 + (lane >> 4) * 8]);
            short8 bf = *(const short8*)(&xT [nt * 16 + (lane & 15)][kt * 32 + (lane >> 4) * 8]);
            acc = mfma_bf16(a, bf, acc);
        }
        int colf = nt * 16 + (lane & 15);
#pragma unroll
        for (int j = 0; j < 4; j++) {
            int row = mt * 16 + (lane >> 4) * 4 + j;
            float y = acc[j] + bias_s[row];
            float sl = slope_s[row];
            y = (y > 0.f) ? y : sl * y;
            ys[row][colf] = y;
        }
    }
    __syncthreads();

    // per-head LN; wave w == head h=w
    const int h = w;
    { // Q: rows 4h..4h+3, norm over 256
        float v0[4]; float s = 0.f, ss = 0.f;
#pragma unroll
        for (int o = 0; o < 4; o++) { float y = ys[h * 4 + o][lane]; v0[o] = y; s += y; ss += y * y; }
#pragma unroll
        for (int m = 1; m < 64; m <<= 1) { s += __shfl_xor(s, m, 64); ss += __shfl_xor(ss, m, 64); }
        float mu = s * (1.f / 256.f), var = ss * (1.f / 256.f) - mu * mu;
        float rs = rsqrtf(var + EPSV);
        size_t base = ((size_t)(h * 8 + b) * 1024 + t) * 256;
#pragma unroll
        for (int o = 0; o < 4; o++) {
            float val = (v0[o] - mu) * rs * qg[(h * 4 + o) * 64 + lane] + qbt[(h * 4 + o) * 64 + lane];
            Qb[base + o * 64 + lane] = f2bf(val);
        }
    }
    { // K: rows 16+4h..
        float v0[4]; float s = 0.f, ss = 0.f;
#pragma unroll
        for (int o = 0; o < 4; o++) { float y = ys[16 + h * 4 + o][lane]; v0[o] = y; s += y; ss += y * y; }
#pragma unroll
        for (int m = 1; m < 64; m <<= 1) { s += __shfl_xor(s, m, 64); ss += __shfl_xor(ss, m, 64); }
        float mu = s * (1.f / 256.f), var = ss * (1.f / 256.f) - mu * mu;
        float rs = rsqrtf(var + EPSV);
        size_t base = ((size_t)(h * 8 + b) * 1024 + t) * 256;
#pragma unroll
        for (int o = 0; o < 4; o++) {
            float val = (v0[o] - mu) * rs * kg[(h * 4 + o) * 64 + lane] + kbt[(h * 4 + o) * 64 + lane];
            Kb[base + o * 64 + lane] = f2bf(val);
        }
    }
    { // V: rows 32+16h..+15, norm over 1024
        float v0[16]; float s = 0.f, ss = 0.f;
#pragma unroll
        for (int o = 0; o < 16; o++) { float y = ys[32 + h * 16 + o][lane]; v0[o] = y; s += y; ss += y * y; }
#pragma unroll
        for (int m = 1; m < 64; m <<= 1) { s += __shfl_xor(s, m, 64); ss += __shfl_xor(ss, m, 64); }
        float mu = s * (1.f / 1024.f), var = ss * (1.f / 1024.f) - mu * mu;
        float rs = rsqrtf(var + EPSV);
        size_t base = ((size_t)(h * 8 + b) * 1024 + t) * 1024;
#pragma unroll
        for (int o = 0; o < 16; o++) {
            float val = (v0[o] - mu) * rs * vg[(h * 16 + o) * 64 + lane] + vbt[(h * 16 + o) * 64 + lane];
            Vb[base + o * 64 + lane] = f2bf(val);
        }
    }
}

// ---------------------------------------------------------------------------
// Kernel 2: transpose V [n][s][d] -> Vt [n][d][s]  (64x64 tiles via LDS)
// ---------------------------------------------------------------------------
__global__ __launch_bounds__(256) void k_vtrans(const u16* __restrict__ Vb, u16* __restrict__ Vt)
{
    __shared__ u16 ts[64][72];
    const int tid = threadIdx.x;
    const int idx = blockIdx.x;               // 32 n * 16 st * 16 dt
    const int n = idx >> 8, rest = idx & 255;
    const int s0 = (rest >> 4) * 64, d0 = (rest & 15) * 64;
    const size_t nb = (size_t)n << 20;

#pragma unroll
    for (int i = 0; i < 2; i++) {
        int chunk = tid + i * 256;            // 0..511 ; 64 rows x 8 chunks of 8 u16
        int row = chunk >> 3, q = chunk & 7;
        uint4 v = *(const uint4*)(Vb + nb + (size_t)(s0 + row) * 1024 + d0 + q * 8);
        *(uint4*)(&ts[row][q * 8]) = v;
    }
    __syncthreads();
#pragma unroll
    for (int i = 0; i < 2; i++) {
        int chunk = tid + i * 256;
        int orow = chunk >> 3, q = chunk & 7; // output d-row, s-chunk
        uint4 o;
        o.x = (unsigned)ts[q * 8 + 0][orow] | ((unsigned)ts[q * 8 + 1][orow] << 16);
        o.y = (unsigned)ts[q * 8 + 2][orow] | ((unsigned)ts[q * 8 + 3][orow] << 16);
        o.z = (unsigned)ts[q * 8 + 4][orow] | ((unsigned)ts[q * 8 + 5][orow] << 16);
        o.w = (unsigned)ts[q * 8 + 6][orow] | ((unsigned)ts[q * 8 + 7][orow] << 16);
        *(uint4*)(Vt + nb + (size_t)(d0 + orow) * 1024 + s0 + q * 8) = o;
    }
}

// ---------------------------------------------------------------------------
// Kernel 3: S = Q K^T / 16, row softmax, write normalized P bf16 [n][t][s].
// One block = one n + 16 q-rows; wave w covers s in [w*256, w*256+256).
// ---------------------------------------------------------------------------
__global__ __launch_bounds__(256) void k_attn(const u16* __restrict__ Qb, const u16* __restrict__ Kb,
                                              u16* __restrict__ P)
{
    const int bid = blockIdx.x;
    const int n = (bid & 7) + ((bid >> 9) << 3);   // XCD swizzle: same n -> same bid%8
    const int qt = (bid >> 3) & 63;
    const int q0 = qt * 16;
    const int tid = threadIdx.x, w = tid >> 6, lane = tid & 63;
    const int grp = lane >> 4, lc = lane & 15;

    const u16* Qn = Qb + ((size_t)n << 18);
    const u16* Kn = Kb + ((size_t)n << 18);

    short8 qf[8];
#pragma unroll
    for (int kt = 0; kt < 8; kt++)
        qf[kt] = *(const short8*)(Qn + (size_t)(q0 + lc) * 256 + kt * 32 + grp * 8);

    f32x4 sacc[16];
#pragma unroll
    for (int ct = 0; ct < 16; ct++) {
        int s0 = w * 256 + ct * 16;
        f32x4 a = {0.f, 0.f, 0.f, 0.f};
#pragma unroll
        for (int kt = 0; kt < 8; kt++) {
            short8 kf = *(const short8*)(Kn + (size_t)(s0 + lc) * 256 + kt * 32 + grp * 8);
            a = mfma_bf16(qf[kt], kf, a);
        }
        sacc[ct] = a;
    }

    float mx[4] = {-1e30f, -1e30f, -1e30f, -1e30f};
#pragma unroll
    for (int ct = 0; ct < 16; ct++)
#pragma unroll
        for (int j = 0; j < 4; j++) {
            float v = sacc[ct][j] * 0.0625f;   // 1/sqrt(256)
            sacc[ct][j] = v;
            mx[j] = fmaxf(mx[j], v);
        }
#pragma unroll
    for (int m = 1; m < 16; m <<= 1)
#pragma unroll
        for (int j = 0; j < 4; j++) mx[j] = fmaxf(mx[j], __shfl_xor(mx[j], m, 64));

    __shared__ float red[2][4][16];
    if (lc == 0) {
#pragma unroll
        for (int j = 0; j < 4; j++) red[0][w][grp * 4 + j] = mx[j];
    }
    __syncthreads();
    float gm[4], sm[4] = {0.f, 0.f, 0.f, 0.f};
#pragma unroll
    for (int j = 0; j < 4; j++) {
        int row = grp * 4 + j;
        gm[j] = fmaxf(fmaxf(red[0][0][row], red[0][1][row]), fmaxf(red[0][2][row], red[0][3][row]));
    }
#pragma unroll
    for (int ct = 0; ct < 16; ct++)
#pragma unroll
        for (int j = 0; j < 4; j++) {
            float p = __expf(sacc[ct][j] - gm[j]);
            sacc[ct][j] = p;
            sm[j] += p;
        }
#pragma unroll
    for (int m = 1; m < 16; m <<= 1)
#pragma unroll
        for (int j = 0; j < 4; j++) sm[j] += __shfl_xor(sm[j], m, 64);
    if (lc == 0) {
#pragma unroll
        for (int j = 0; j < 4; j++) red[1][w][grp * 4 + j] = sm[j];
    }
    __syncthreads();

    u16* Pn = P + ((size_t)n << 20);
    float inv[4];
#pragma unroll
    for (int j = 0; j < 4; j++) {
        int row = grp * 4 + j;
        float tot = red[1][0][row] + red[1][1][row] + red[1][2][row] + red[1][3][row];
        inv[j] = 1.f / tot;
    }
#pragma unroll
    for (int ct = 0; ct < 16; ct++)
#pragma unroll
        for (int j = 0; j < 4; j++) {
            Pn[(size_t)(q0 + grp * 4 + j) * 1024 + w * 256 + ct * 16 + lc] = f2bf(sacc[ct][j] * inv[j]);
        }
}

// ---------------------------------------------------------------------------
// Kernel 4: A = P (1024x1024) x V (1024x1024) per n ; m97-style 128x128 tile,
// BK=32, global_load_lds staging. Epilogue scatters fp32 into [B,C,T,F].
// ---------------------------------------------------------------------------
__global__ __launch_bounds__(256) void k_pv(const u16* __restrict__ P, const u16* __restrict__ Vt,
                                            float* __restrict__ out)
{
    const int bid = blockIdx.x;
    const int n = (bid & 7) + ((bid >> 9) << 3);
    const int tile = (bid >> 3) & 63;
    const int tm = tile >> 3, tn = tile & 7;
    const int tid = threadIdx.x, w = tid >> 6, lane = tid & 63;
    const int wr = w >> 1, wc = w & 1;
    const int lc = lane & 15, grp = lane >> 4;

    __shared__ u16 As[128 * 32];
    __shared__ u16 Bs[128 * 32];

    const u16* Pa = P  + ((size_t)n << 20) + (size_t)tm * 128 * 1024;
    const u16* Va = Vt + ((size_t)n << 20) + (size_t)tn * 128 * 1024;

    f32x4 acc[4][4];
#pragma unroll
    for (int mi = 0; mi < 4; mi++)
#pragma unroll
        for (int ni = 0; ni < 4; ni++) acc[mi][ni] = (f32x4){0.f, 0.f, 0.f, 0.f};

    for (int ks = 0; ks < 32; ks++) {
        int k0 = ks * 32;
#pragma unroll
        for (int jj = 0; jj < 2; jj++) {
            int seg = jj * 4 + w;             // 0..7
            int chunk = seg * 64 + lane;      // 8-u16 chunk id
            int row = chunk >> 2, q = chunk & 3;
            gload_lds16(Pa + (size_t)row * 1024 + k0 + q * 8, As + seg * 512);
            gload_lds16(Va + (size_t)row * 1024 + k0 + q * 8, Bs + seg * 512);
        }
        __syncthreads();
        short8 af[4], bfr[4];
#pragma unroll
        for (int mi = 0; mi < 4; mi++)
            af[mi] = *(const short8*)(As + (wr * 64 + mi * 16 + lc) * 32 + grp * 8);
#pragma unroll
        for (int ni = 0; ni < 4; ni++)
            bfr[ni] = *(const short8*)(Bs + (wc * 64 + ni * 16 + lc) * 32 + grp * 8);
#pragma unroll
        for (int mi = 0; mi < 4; mi++)
#pragma unroll
            for (int ni = 0; ni < 4; ni++)
                acc[mi][ni] = mfma_bf16(af[mi], bfr[ni], acc[mi][ni]);
        __syncthreads();
    }

    const int h = n >> 3, b = n & 7;
#pragma unroll
    for (int mi = 0; mi < 4; mi++)
#pragma unroll
        for (int ni = 0; ni < 4; ni++) {
            int d = tn * 128 + wc * 64 + ni * 16 + lc;
            int c = h * 16 + (d >> 6), f = d & 63;
#pragma unroll
            for (int j = 0; j < 4; j++) {
                int trow = tm * 128 + wr * 64 + mi * 16 + grp * 4 + j;
                out[(((size_t)b * 64 + c) * 1024 + trow) * 64 + f] = acc[mi][ni][j];
            }
        }
}

// ---------------------------------------------------------------------------
// Kernel 5: final conv block (64->64) + PReLU + LN(4096) + affine + residual,
// in-place on d_out. One block per (b,t).
// ---------------------------------------------------------------------------
__global__ __launch_bounds__(256) void k_final(
    const float* __restrict__ Ain, const float* __restrict__ x,
    const float* __restrict__ lw, const float* __restrict__ lbias, const float* __restrict__ la,
    const float* __restrict__ lg, const float* __restrict__ lbt, float* __restrict__ out)
{
    __shared__ u16 AT[64][72];     // [f][c]
    __shared__ u16 lwb[64][72];    // [o][c]
    __shared__ float ys[64][64];
    __shared__ float red[8];

    const int tid = threadIdx.x, w = tid >> 6, lane = tid & 63;
    const int b = blockIdx.x >> 10, t = blockIdx.x & 1023;
    const int lc = lane & 15, grp = lane >> 4;

#pragma unroll
    for (int i = 0; i < 16; i++) {
        int idx = tid + i * 256;
        lwb[idx >> 6][idx & 63] = f2bf(lw[idx]);
    }
    const float* Abt = Ain + ((size_t)(b * 64) * 1024 + t) * 64;
#pragma unroll
    for (int k = 0; k < 4; k++) {
        int chunk = tid + k * 256;
        int c = chunk >> 4, q = chunk & 15;
        float4 v = *(const float4*)(Abt + (size_t)c * 65536 + q * 4);
        AT[q * 4 + 0][c] = f2bf(v.x);
        AT[q * 4 + 1][c] = f2bf(v.y);
        AT[q * 4 + 2][c] = f2bf(v.z);
        AT[q * 4 + 3][c] = f2bf(v.w);
    }
    __syncthreads();

    const float slope = la[0];
    float psum = 0.f, psq = 0.f;
#pragma unroll
    for (int nt = 0; nt < 4; nt++) {
        f32x4 acc = {0.f, 0.f, 0.f, 0.f};
#pragma unroll
        for (int kt = 0; kt < 2; kt++) {
            short8 a  = *(const short8*)(&lwb[w * 16 + lc][kt * 32 + grp * 8]);
            short8 bf = *(const short8*)(&AT [nt * 16 + lc][kt * 32 + grp * 8]);
            acc = mfma_bf16(a, bf, acc);
        }
#pragma unroll
        for (int j = 0; j < 4; j++) {
            int row = w * 16 + grp * 4 + j;
            float y = acc[j] + lbias[row];
            y = (y > 0.f) ? y : slope * y;
            ys[row][nt * 16 + lc] = y;
            psum += y; psq += y * y;
        }
    }
#pragma unroll
    for (int m = 1; m < 64; m <<= 1) { psum += __shfl_xor(psum, m, 64); psq += __shfl_xor(psq, m, 64); }
    if (lane == 0) { red[w] = psum; red[4 + w] = psq; }
    __syncthreads();
    float S  = red[0] + red[1] + red[2] + red[3];
    float SS = red[4] + red[5] + red[6] + red[7];
    float mu = S * (1.f / 4096.f), var = SS * (1.f / 4096.f) - mu * mu;
    float rs = rsqrtf(var + EPSV);

    for (int idx = tid; idx < 4096; idx += 256) {
        int o = idx >> 6, f = idx & 63;
        size_t gi = ((size_t)(b * 64 + o) * 1024 + t) * 64 + f;
        out[gi] = (ys[o][f] - mu) * rs * lg[idx] + lbt[idx] + x[gi];
    }
}

// ---------------------------------------------------------------------------
extern "C" void kernel_launch(void* const* d_in, const int* in_sizes, int n_in,
                              void* d_out, int out_size, void* d_ws, size_t ws_size,
                              hipStream_t stream)
{
    const float* x    = (const float*)d_in[0];
    const float* qw   = (const float*)d_in[1];
    const float* qb   = (const float*)d_in[2];
    const float* qa   = (const float*)d_in[3];
    const float* qg   = (const float*)d_in[4];
    const float* qbt  = (const float*)d_in[5];
    const float* kw   = (const float*)d_in[6];
    const float* kb   = (const float*)d_in[7];
    const float* ka   = (const float*)d_in[8];
    const float* kg   = (const float*)d_in[9];
    const float* kbt  = (const float*)d_in[10];
    const float* vw   = (const float*)d_in[11];
    const float* vb   = (const float*)d_in[12];
    const float* va   = (const float*)d_in[13];
    const float* vg   = (const float*)d_in[14];
    const float* vbt  = (const float*)d_in[15];
    const float* lw   = (const float*)d_in[16];
    const float* lb   = (const float*)d_in[17];
    const float* la   = (const float*)d_in[18];
    const float* lg   = (const float*)d_in[19];
    const float* lbt  = (const float*)d_in[20];

    float* out = (float*)d_out;

    // Scratch layout:
    //   ws[0          .. 64MB) : Vb [32][1024][1024] bf16 ; later aliased by P
    //   ws[64MB       ..128MB) : Vt [32][1024][1024] bf16
    //   d_out[0..16MB) : Qb bf16 ; d_out[16..32MB) : Kb bf16 (dead before k_pv writes)
    u16* Vb = (u16*)d_ws;
    u16* Vt = (u16*)((char*)d_ws + ((size_t)64 << 20));
    u16* P  = Vb;
    u16* Qb = (u16*)d_out;
    u16* Kb = (u16*)((char*)d_out + ((size_t)16 << 20));

    k_qkv<<<dim3(8192), dim3(256), 0, stream>>>(x, qw, qb, qa, qg, qbt,
                                                kw, kb, ka, kg, kbt,
                                                vw, vb, va, vg, vbt, Qb, Kb, Vb);
    k_vtrans<<<dim3(8192), dim3(256), 0, stream>>>(Vb, Vt);
    k_attn<<<dim3(2048), dim3(256), 0, stream>>>(Qb, Kb, P);
    k_pv<<<dim3(2048), dim3(256), 0, stream>>>(P, Vt, out);
    k_final<<<dim3(8192), dim3(256), 0, stream>>>(out, x, lw, lb, la, lg, lbt, out);
}

// Round 3
// 370.738 us; speedup vs baseline: 1.2300x; 1.2300x over previous
//
#include <hip/hip_runtime.h>

typedef unsigned short u16;
typedef __attribute__((ext_vector_type(8))) short short8;
typedef __attribute__((ext_vector_type(4))) float f32x4;

#define EPSV 1e-5f

__device__ __forceinline__ u16 f2bf(float f) {
    unsigned u = __float_as_uint(f);
    u += 0x7fffu + ((u >> 16) & 1u);
    return (u16)(u >> 16);
}

__device__ __forceinline__ f32x4 mfma_bf16(short8 a, short8 b, f32x4 c) {
    return __builtin_amdgcn_mfma_f32_16x16x32_bf16(a, b, c, 0, 0, 0);
}

__device__ __forceinline__ void gload_lds16(const void* g, void* l) {
    __builtin_amdgcn_global_load_lds((const __attribute__((address_space(1))) void*)g,
                                     (__attribute__((address_space(3))) void*)l, 16, 0, 0);
}

// ---------------------------------------------------------------------------
// Kernel 1: fused QKV 1x1-conv + bias + PReLU + per-head LayerNorm + affine.
// One block per (b,t). Conv done as 96x64 @ 64x64 bf16 MFMA GEMM.
// Q/K written as bf16 [n=h*8+b][t][d=o*64+f] (d=256); V as [n][t][d=o*64+f] (d=1024).
// ---------------------------------------------------------------------------
__global__ __launch_bounds__(256) void k_qkv(
    const float* __restrict__ x,
    const float* __restrict__ qw, const float* __restrict__ qb, const float* __restrict__ qa,
    const float* __restrict__ qg, const float* __restrict__ qbt,
    const float* __restrict__ kw, const float* __restrict__ kb, const float* __restrict__ ka,
    const float* __restrict__ kg, const float* __restrict__ kbt,
    const float* __restrict__ vw, const float* __restrict__ vb, const float* __restrict__ va,
    const float* __restrict__ vg, const float* __restrict__ vbt,
    u16* __restrict__ Qb, u16* __restrict__ Kb, u16* __restrict__ Vb)
{
    __shared__ u16 xT[64][72];     // [f][c] bf16 (transposed x slice)
    __shared__ u16 wsb[96][72];    // [och][c] bf16 (rows 0-15 Q, 16-31 K, 32-95 V)
    __shared__ float ys[96][64];   // PReLU'd conv output [och][f]
    __shared__ float bias_s[96], slope_s[96];

    const int tid = threadIdx.x, w = tid >> 6, lane = tid & 63;
    const int b = blockIdx.x >> 10, t = blockIdx.x & 1023;

    // stage weights (fp32 -> bf16)
#pragma unroll
    for (int i = 0; i < 24; i++) {
        int idx = tid + i * 256;           // 0..6143
        int row = idx >> 6, c = idx & 63;
        float wv = (row < 16) ? qw[idx] : ((row < 32) ? kw[idx - 1024] : vw[idx - 2048]);
        wsb[row][c] = f2bf(wv);
    }
    if (tid < 96) {
        int row = tid; float bv, sv;
        if (row < 16)      { bv = qb[row];      sv = qa[row >> 2]; }
        else if (row < 32) { bv = kb[row - 16]; sv = ka[(row - 16) >> 2]; }
        else               { bv = vb[row - 32]; sv = va[(row - 32) >> 4]; }
        bias_s[row] = bv; slope_s[row] = sv;
    }
    // stage x[b,:,t,:] transposed -> xT[f][c]
    const float* xbt = x + ((size_t)(b * 64) * 1024 + t) * 64;
#pragma unroll
    for (int k = 0; k < 4; k++) {
        int chunk = tid + k * 256;        // 0..1023  (64 c-rows x 16 float4)
        int c = chunk >> 4, q = chunk & 15;
        float4 v = *(const float4*)(xbt + (size_t)c * 65536 + q * 4);
        xT[q * 4 + 0][c] = f2bf(v.x);
        xT[q * 4 + 1][c] = f2bf(v.y);
        xT[q * 4 + 2][c] = f2bf(v.z);
        xT[q * 4 + 3][c] = f2bf(v.w);
    }
    __syncthreads();

    // conv: y[o][f] = sum_c w[o][c] x[c][f] ; 6x4 tiles of 16x16, K=64
#pragma unroll
    for (int i = 0; i < 6; i++) {
        int tile = w * 6 + i;
        int mt = tile >> 2, nt = tile & 3;
        f32x4 acc = {0.f, 0.f, 0.f, 0.f};
#pragma unroll
        for (int kt = 0; kt < 2; kt++) {
            short8 a  = *(const short8*)(&wsb[mt * 16 + (lane & 15)][kt * 32 + (lane >> 4) * 8]);
            short8 bf = *(const short8*)(&xT [nt * 16 + (lane & 15)][kt * 32 + (lane >> 4) * 8]);
            acc = mfma_bf16(a, bf, acc);
        }
        int colf = nt * 16 + (lane & 15);
#pragma unroll
        for (int j = 0; j < 4; j++) {
            int row = mt * 16 + (lane >> 4) * 4 + j;
            float y = acc[j] + bias_s[row];
            float sl = slope_s[row];
            y = (y > 0.f) ? y : sl * y;
            ys[row][colf] = y;
        }
    }
    __syncthreads();

    // per-head LN; wave w == head h=w
    const int h = w;
    { // Q: rows 4h..4h+3, norm over 256
        float v0[4]; float s = 0.f, ss = 0.f;
#pragma unroll
        for (int o = 0; o < 4; o++) { float y = ys[h * 4 + o][lane]; v0[o] = y; s += y; ss += y * y; }
#pragma unroll
        for (int m = 1; m < 64; m <<= 1) { s += __shfl_xor(s, m, 64); ss += __shfl_xor(ss, m, 64); }
        float mu = s * (1.f / 256.f), var = ss * (1.f / 256.f) - mu * mu;
        float rs = rsqrtf(var + EPSV);
        size_t base = ((size_t)(h * 8 + b) * 1024 + t) * 256;
#pragma unroll
        for (int o = 0; o < 4; o++) {
            float val = (v0[o] - mu) * rs * qg[(h * 4 + o) * 64 + lane] + qbt[(h * 4 + o) * 64 + lane];
            Qb[base + o * 64 + lane] = f2bf(val);
        }
    }
    { // K: rows 16+4h..
        float v0[4]; float s = 0.f, ss = 0.f;
#pragma unroll
        for (int o = 0; o < 4; o++) { float y = ys[16 + h * 4 + o][lane]; v0[o] = y; s += y; ss += y * y; }
#pragma unroll
        for (int m = 1; m < 64; m <<= 1) { s += __shfl_xor(s, m, 64); ss += __shfl_xor(ss, m, 64); }
        float mu = s * (1.f / 256.f), var = ss * (1.f / 256.f) - mu * mu;
        float rs = rsqrtf(var + EPSV);
        size_t base = ((size_t)(h * 8 + b) * 1024 + t) * 256;
#pragma unroll
        for (int o = 0; o < 4; o++) {
            float val = (v0[o] - mu) * rs * kg[(h * 4 + o) * 64 + lane] + kbt[(h * 4 + o) * 64 + lane];
            Kb[base + o * 64 + lane] = f2bf(val);
        }
    }
    { // V: rows 32+16h..+15, norm over 1024
        float v0[16]; float s = 0.f, ss = 0.f;
#pragma unroll
        for (int o = 0; o < 16; o++) { float y = ys[32 + h * 16 + o][lane]; v0[o] = y; s += y; ss += y * y; }
#pragma unroll
        for (int m = 1; m < 64; m <<= 1) { s += __shfl_xor(s, m, 64); ss += __shfl_xor(ss, m, 64); }
        float mu = s * (1.f / 1024.f), var = ss * (1.f / 1024.f) - mu * mu;
        float rs = rsqrtf(var + EPSV);
        size_t base = ((size_t)(h * 8 + b) * 1024 + t) * 1024;
#pragma unroll
        for (int o = 0; o < 16; o++) {
            float val = (v0[o] - mu) * rs * vg[(h * 16 + o) * 64 + lane] + vbt[(h * 16 + o) * 64 + lane];
            Vb[base + o * 64 + lane] = f2bf(val);
        }
    }
}

// ---------------------------------------------------------------------------
// Kernel 2: transpose V [n][s][d] -> Vt [n][d][s]  (64x64 tiles via LDS)
// ---------------------------------------------------------------------------
__global__ __launch_bounds__(256) void k_vtrans(const u16* __restrict__ Vb, u16* __restrict__ Vt)
{
    __shared__ u16 ts[64][72];
    const int tid = threadIdx.x;
    const int idx = blockIdx.x;               // 32 n * 16 st * 16 dt
    const int n = idx >> 8, rest = idx & 255;
    const int s0 = (rest >> 4) * 64, d0 = (rest & 15) * 64;
    const size_t nb = (size_t)n << 20;

#pragma unroll
    for (int i = 0; i < 2; i++) {
        int chunk = tid + i * 256;            // 0..511 ; 64 rows x 8 chunks of 8 u16
        int row = chunk >> 3, q = chunk & 7;
        uint4 v = *(const uint4*)(Vb + nb + (size_t)(s0 + row) * 1024 + d0 + q * 8);
        *(uint4*)(&ts[row][q * 8]) = v;
    }
    __syncthreads();
#pragma unroll
    for (int i = 0; i < 2; i++) {
        int chunk = tid + i * 256;
        int orow = chunk >> 3, q = chunk & 7; // output d-row, s-chunk
        uint4 o;
        o.x = (unsigned)ts[q * 8 + 0][orow] | ((unsigned)ts[q * 8 + 1][orow] << 16);
        o.y = (unsigned)ts[q * 8 + 2][orow] | ((unsigned)ts[q * 8 + 3][orow] << 16);
        o.z = (unsigned)ts[q * 8 + 4][orow] | ((unsigned)ts[q * 8 + 5][orow] << 16);
        o.w = (unsigned)ts[q * 8 + 6][orow] | ((unsigned)ts[q * 8 + 7][orow] << 16);
        *(uint4*)(Vt + nb + (size_t)(d0 + orow) * 1024 + s0 + q * 8) = o;
    }
}

// ---------------------------------------------------------------------------
// Kernel 3: S = Q K^T / 16, row softmax, write normalized P bf16 [n][t][s].
// One block = one n + 16 q-rows; wave w covers s in [w*256, w*256+256).
// K staged per-wave in LDS (global_load_lds w16, XOR-swizzled via pre-swizzled
// global source + swizzled read), sync'd with the PROVEN m97 barrier pattern:
// stage -> __syncthreads (full vmcnt drain) -> MFMA -> __syncthreads.
// ---------------------------------------------------------------------------
__global__ __launch_bounds__(256) void k_attn(const u16* __restrict__ Qb, const u16* __restrict__ Kb,
                                              u16* __restrict__ P)
{
    __shared__ u16 Ks[4][16 * 256];        // 32 KB: per-wave 16x256 bf16 K tile
    __shared__ float red[2][4][16];

    const int bid = blockIdx.x;
    const int n = (bid & 7) + ((bid >> 9) << 3);   // XCD swizzle: same n -> same bid%8
    const int qt = (bid >> 3) & 63;
    const int q0 = qt * 16;
    const int tid = threadIdx.x, w = tid >> 6, lane = tid & 63;
    const int grp = lane >> 4, lc = lane & 15;

    const u16* Qn = Qb + ((size_t)n << 18);
    const u16* Kn = Kb + ((size_t)n << 18);

    // Q fragments (one-time)
    short8 qf[8];
#pragma unroll
    for (int kt = 0; kt < 8; kt++)
        qf[kt] = *(const short8*)(Qn + (size_t)(q0 + lc) * 256 + kt * 32 + grp * 8);

    u16* KsW = Ks[w];
    const int l_row = lane >> 5;          // 0..1 (2 rows per 1KB staging call)
    const int l_cs = (lane & 31) * 8;     // u16 chunk offset within row

    f32x4 sacc[16];
#pragma unroll
    for (int st = 0; st < 16; st++) {
        int s0 = w * 256 + st * 16;
        // stage 16 s-rows x 256 d: LDS linear, global source pre-swizzled
        // (chunk index XOR (row&7)) so the read-side XOR lands on K-major data.
#pragma unroll
        for (int c = 0; c < 8; c++) {
            int row = c * 2 + l_row;
            int col = l_cs ^ ((row & 7) << 3);
            gload_lds16(Kn + (size_t)(s0 + row) * 256 + col, KsW + c * 512);
        }
        __syncthreads();                   // drains vmcnt(0): tile visible
        f32x4 a = {0.f, 0.f, 0.f, 0.f};
#pragma unroll
        for (int kt = 0; kt < 8; kt++) {
            int off = lc * 256 + ((kt * 32 + grp * 8) ^ ((lc & 7) << 3));
            short8 kf = *(const short8*)(KsW + off);
            a = mfma_bf16(qf[kt], kf, a);
        }
        sacc[st] = a;
        __syncthreads();                   // reads done before next stage lands
    }

    // ---- softmax over the full 1024 columns (4 waves x 256 each) ----
    float mx[4] = {-1e30f, -1e30f, -1e30f, -1e30f};
#pragma unroll
    for (int st = 0; st < 16; st++)
#pragma unroll
        for (int j = 0; j < 4; j++) {
            float v = sacc[st][j] * 0.0625f;   // 1/sqrt(256)
            sacc[st][j] = v;
            mx[j] = fmaxf(mx[j], v);
        }
#pragma unroll
    for (int m = 1; m < 16; m <<= 1)
#pragma unroll
        for (int j = 0; j < 4; j++) mx[j] = fmaxf(mx[j], __shfl_xor(mx[j], m, 64));

    if (lc == 0) {
#pragma unroll
        for (int j = 0; j < 4; j++) red[0][w][grp * 4 + j] = mx[j];
    }
    __syncthreads();
    float gm[4], sm[4] = {0.f, 0.f, 0.f, 0.f};
#pragma unroll
    for (int j = 0; j < 4; j++) {
        int row = grp * 4 + j;
        gm[j] = fmaxf(fmaxf(red[0][0][row], red[0][1][row]), fmaxf(red[0][2][row], red[0][3][row]));
    }
#pragma unroll
    for (int st = 0; st < 16; st++)
#pragma unroll
        for (int j = 0; j < 4; j++) {
            float p = __expf(sacc[st][j] - gm[j]);
            sacc[st][j] = p;
            sm[j] += p;
        }
#pragma unroll
    for (int m = 1; m < 16; m <<= 1)
#pragma unroll
        for (int j = 0; j < 4; j++) sm[j] += __shfl_xor(sm[j], m, 64);
    if (lc == 0) {
#pragma unroll
        for (int j = 0; j < 4; j++) red[1][w][grp * 4 + j] = sm[j];
    }
    __syncthreads();

    u16* Pn = P + ((size_t)n << 20);
    float inv[4];
#pragma unroll
    for (int j = 0; j < 4; j++) {
        int row = grp * 4 + j;
        float tot = red[1][0][row] + red[1][1][row] + red[1][2][row] + red[1][3][row];
        inv[j] = 1.f / tot;
    }
#pragma unroll
    for (int st = 0; st < 16; st++)
#pragma unroll
        for (int j = 0; j < 4; j++) {
            Pn[(size_t)(q0 + grp * 4 + j) * 1024 + w * 256 + st * 16 + lc] = f2bf(sacc[st][j] * inv[j]);
        }
}

// ---------------------------------------------------------------------------
// Kernel 4: A = P (1024x1024) x V (1024x1024) per n ; m97-style 128x128 tile,
// BK=32, global_load_lds staging. Epilogue scatters fp32 into [B,C,T,F].
// ---------------------------------------------------------------------------
__global__ __launch_bounds__(256) void k_pv(const u16* __restrict__ P, const u16* __restrict__ Vt,
                                            float* __restrict__ out)
{
    const int bid = blockIdx.x;
    const int n = (bid & 7) + ((bid >> 9) << 3);
    const int tile = (bid >> 3) & 63;
    const int tm = tile >> 3, tn = tile & 7;
    const int tid = threadIdx.x, w = tid >> 6, lane = tid & 63;
    const int wr = w >> 1, wc = w & 1;
    const int lc = lane & 15, grp = lane >> 4;

    __shared__ u16 As[128 * 32];
    __shared__ u16 Bs[128 * 32];

    const u16* Pa = P  + ((size_t)n << 20) + (size_t)tm * 128 * 1024;
    const u16* Va = Vt + ((size_t)n << 20) + (size_t)tn * 128 * 1024;

    f32x4 acc[4][4];
#pragma unroll
    for (int mi = 0; mi < 4; mi++)
#pragma unroll
        for (int ni = 0; ni < 4; ni++) acc[mi][ni] = (f32x4){0.f, 0.f, 0.f, 0.f};

    for (int ks = 0; ks < 32; ks++) {
        int k0 = ks * 32;
#pragma unroll
        for (int jj = 0; jj < 2; jj++) {
            int seg = jj * 4 + w;             // 0..7
            int chunk = seg * 64 + lane;      // 8-u16 chunk id
            int row = chunk >> 2, q = chunk & 3;
            gload_lds16(Pa + (size_t)row * 1024 + k0 + q * 8, As + seg * 512);
            gload_lds16(Va + (size_t)row * 1024 + k0 + q * 8, Bs + seg * 512);
        }
        __syncthreads();
        short8 af[4], bfr[4];
#pragma unroll
        for (int mi = 0; mi < 4; mi++)
            af[mi] = *(const short8*)(As + (wr * 64 + mi * 16 + lc) * 32 + grp * 8);
#pragma unroll
        for (int ni = 0; ni < 4; ni++)
            bfr[ni] = *(const short8*)(Bs + (wc * 64 + ni * 16 + lc) * 32 + grp * 8);
#pragma unroll
        for (int mi = 0; mi < 4; mi++)
#pragma unroll
            for (int ni = 0; ni < 4; ni++)
                acc[mi][ni] = mfma_bf16(af[mi], bfr[ni], acc[mi][ni]);
        __syncthreads();
    }

    const int h = n >> 3, b = n & 7;
#pragma unroll
    for (int mi = 0; mi < 4; mi++)
#pragma unroll
        for (int ni = 0; ni < 4; ni++) {
            int d = tn * 128 + wc * 64 + ni * 16 + lc;
            int c = h * 16 + (d >> 6), f = d & 63;
#pragma unroll
            for (int j = 0; j < 4; j++) {
                int trow = tm * 128 + wr * 64 + mi * 16 + grp * 4 + j;
                out[(((size_t)b * 64 + c) * 1024 + trow) * 64 + f] = acc[mi][ni][j];
            }
        }
}

// ---------------------------------------------------------------------------
// Kernel 5: final conv block (64->64) + PReLU + LN(4096) + affine + residual,
// in-place on d_out. One block per (b,t).
// ---------------------------------------------------------------------------
__global__ __launch_bounds__(256) void k_final(
    const float* __restrict__ Ain, const float* __restrict__ x,
    const float* __restrict__ lw, const float* __restrict__ lbias, const float* __restrict__ la,
    const float* __restrict__ lg, const float* __restrict__ lbt, float* __restrict__ out)
{
    __shared__ u16 AT[64][72];     // [f][c]
    __shared__ u16 lwb[64][72];    // [o][c]
    __shared__ float ys[64][64];
    __shared__ float red[8];

    const int tid = threadIdx.x, w = tid >> 6, lane = tid & 63;
    const int b = blockIdx.x >> 10, t = blockIdx.x & 1023;
    const int lc = lane & 15, grp = lane >> 4;

#pragma unroll
    for (int i = 0; i < 16; i++) {
        int idx = tid + i * 256;
        lwb[idx >> 6][idx & 63] = f2bf(lw[idx]);
    }
    const float* Abt = Ain + ((size_t)(b * 64) * 1024 + t) * 64;
#pragma unroll
    for (int k = 0; k < 4; k++) {
        int chunk = tid + k * 256;
        int c = chunk >> 4, q = chunk & 15;
        float4 v = *(const float4*)(Abt + (size_t)c * 65536 + q * 4);
        AT[q * 4 + 0][c] = f2bf(v.x);
        AT[q * 4 + 1][c] = f2bf(v.y);
        AT[q * 4 + 2][c] = f2bf(v.z);
        AT[q * 4 + 3][c] = f2bf(v.w);
    }
    __syncthreads();

    const float slope = la[0];
    float psum = 0.f, psq = 0.f;
#pragma unroll
    for (int nt = 0; nt < 4; nt++) {
        f32x4 acc = {0.f, 0.f, 0.f, 0.f};
#pragma unroll
        for (int kt = 0; kt < 2; kt++) {
            short8 a  = *(const short8*)(&lwb[w * 16 + lc][kt * 32 + grp * 8]);
            short8 bf = *(const short8*)(&AT [nt * 16 + lc][kt * 32 + grp * 8]);
            acc = mfma_bf16(a, bf, acc);
        }
#pragma unroll
        for (int j = 0; j < 4; j++) {
            int row = w * 16 + grp * 4 + j;
            float y = acc[j] + lbias[row];
            y = (y > 0.f) ? y : slope * y;
            ys[row][nt * 16 + lc] = y;
            psum += y; psq += y * y;
        }
    }
#pragma unroll
    for (int m = 1; m < 64; m <<= 1) { psum += __shfl_xor(psum, m, 64); psq += __shfl_xor(psq, m, 64); }
    if (lane == 0) { red[w] = psum; red[4 + w] = psq; }
    __syncthreads();
    float S  = red[0] + red[1] + red[2] + red[3];
    float SS = red[4] + red[5] + red[6] + red[7];
    float mu = S * (1.f / 4096.f), var = SS * (1.f / 4096.f) - mu * mu;
    float rs = rsqrtf(var + EPSV);

    for (int idx = tid; idx < 4096; idx += 256) {
        int o = idx >> 6, f = idx & 63;
        size_t gi = ((size_t)(b * 64 + o) * 1024 + t) * 64 + f;
        out[gi] = (ys[o][f] - mu) * rs * lg[idx] + lbt[idx] + x[gi];
    }
}

// ---------------------------------------------------------------------------
extern "C" void kernel_launch(void* const* d_in, const int* in_sizes, int n_in,
                              void* d_out, int out_size, void* d_ws, size_t ws_size,
                              hipStream_t stream)
{
    const float* x    = (const float*)d_in[0];
    const float* qw   = (const float*)d_in[1];
    const float* qb   = (const float*)d_in[2];
    const float* qa   = (const float*)d_in[3];
    const float* qg   = (const float*)d_in[4];
    const float* qbt  = (const float*)d_in[5];
    const float* kw   = (const float*)d_in[6];
    const float* kb   = (const float*)d_in[7];
    const float* ka   = (const float*)d_in[8];
    const float* kg   = (const float*)d_in[9];
    const float* kbt  = (const float*)d_in[10];
    const float* vw   = (const float*)d_in[11];
    const float* vb   = (const float*)d_in[12];
    const float* va   = (const float*)d_in[13];
    const float* vg   = (const float*)d_in[14];
    const float* vbt  = (const float*)d_in[15];
    const float* lw   = (const float*)d_in[16];
    const float* lb   = (const float*)d_in[17];
    const float* la   = (const float*)d_in[18];
    const float* lg   = (const float*)d_in[19];
    const float* lbt  = (const float*)d_in[20];

    float* out = (float*)d_out;

    // Scratch layout:
    //   ws[0          .. 64MB) : Vb [32][1024][1024] bf16 ; later aliased by P
    //   ws[64MB       ..128MB) : Vt [32][1024][1024] bf16
    //   d_out[0..16MB) : Qb bf16 ; d_out[16..32MB) : Kb bf16 (dead before k_pv writes)
    u16* Vb = (u16*)d_ws;
    u16* Vt = (u16*)((char*)d_ws + ((size_t)64 << 20));
    u16* P  = Vb;
    u16* Qb = (u16*)d_out;
    u16* Kb = (u16*)((char*)d_out + ((size_t)16 << 20));

    k_qkv<<<dim3(8192), dim3(256), 0, stream>>>(x, qw, qb, qa, qg, qbt,
                                                kw, kb, ka, kg, kbt,
                                                vw, vb, va, vg, vbt, Qb, Kb, Vb);
    k_vtrans<<<dim3(8192), dim3(256), 0, stream>>>(Vb, Vt);
    k_attn<<<dim3(2048), dim3(256), 0, stream>>>(Qb, Kb, P);
    k_pv<<<dim3(2048), dim3(256), 0, stream>>>(P, Vt, out);
    k_final<<<dim3(8192), dim3(256), 0, stream>>>(out, x, lw, lb, la, lg, lbt, out);
}

// Round 4
// 337.562 us; speedup vs baseline: 1.3509x; 1.0983x over previous
//
#include <hip/hip_runtime.h>

typedef unsigned short u16;
typedef __attribute__((ext_vector_type(8))) short short8;
typedef __attribute__((ext_vector_type(4))) float f32x4;

#define EPSV 1e-5f

__device__ __forceinline__ u16 f2bf(float f) {
    unsigned u = __float_as_uint(f);
    u += 0x7fffu + ((u >> 16) & 1u);
    return (u16)(u >> 16);
}

__device__ __forceinline__ f32x4 mfma_bf16(short8 a, short8 b, f32x4 c) {
    return __builtin_amdgcn_mfma_f32_16x16x32_bf16(a, b, c, 0, 0, 0);
}

__device__ __forceinline__ void gload_lds16(const void* g, void* l) {
    __builtin_amdgcn_global_load_lds((const __attribute__((address_space(1))) void*)g,
                                     (__attribute__((address_space(3))) void*)l, 16, 0, 0);
}

// ---------------------------------------------------------------------------
// Kernel 1: fused QKV 1x1-conv + bias + PReLU + per-head LayerNorm + affine.
// One block per (b,t). Conv done as 96x64 @ 64x64 bf16 MFMA GEMM.
// Q/K written as bf16 [n=h*8+b][t][d=o*64+f] (d=256); V as [n][t][d=o*64+f] (d=1024).
// ---------------------------------------------------------------------------
__global__ __launch_bounds__(256) void k_qkv(
    const float* __restrict__ x,
    const float* __restrict__ qw, const float* __restrict__ qb, const float* __restrict__ qa,
    const float* __restrict__ qg, const float* __restrict__ qbt,
    const float* __restrict__ kw, const float* __restrict__ kb, const float* __restrict__ ka,
    const float* __restrict__ kg, const float* __restrict__ kbt,
    const float* __restrict__ vw, const float* __restrict__ vb, const float* __restrict__ va,
    const float* __restrict__ vg, const float* __restrict__ vbt,
    u16* __restrict__ Qb, u16* __restrict__ Kb, u16* __restrict__ Vb)
{
    __shared__ u16 xT[64][72];     // [f][c] bf16 (transposed x slice)
    __shared__ u16 wsb[96][72];    // [och][c] bf16 (rows 0-15 Q, 16-31 K, 32-95 V)
    __shared__ float ys[96][64];   // PReLU'd conv output [och][f]
    __shared__ float bias_s[96], slope_s[96];

    const int tid = threadIdx.x, w = tid >> 6, lane = tid & 63;
    const int b = blockIdx.x >> 10, t = blockIdx.x & 1023;

    // stage weights (fp32 -> bf16)
#pragma unroll
    for (int i = 0; i < 24; i++) {
        int idx = tid + i * 256;           // 0..6143
        int row = idx >> 6, c = idx & 63;
        float wv = (row < 16) ? qw[idx] : ((row < 32) ? kw[idx - 1024] : vw[idx - 2048]);
        wsb[row][c] = f2bf(wv);
    }
    if (tid < 96) {
        int row = tid; float bv, sv;
        if (row < 16)      { bv = qb[row];      sv = qa[row >> 2]; }
        else if (row < 32) { bv = kb[row - 16]; sv = ka[(row - 16) >> 2]; }
        else               { bv = vb[row - 32]; sv = va[(row - 32) >> 4]; }
        bias_s[row] = bv; slope_s[row] = sv;
    }
    // stage x[b,:,t,:] transposed -> xT[f][c]
    const float* xbt = x + ((size_t)(b * 64) * 1024 + t) * 64;
#pragma unroll
    for (int k = 0; k < 4; k++) {
        int chunk = tid + k * 256;        // 0..1023  (64 c-rows x 16 float4)
        int c = chunk >> 4, q = chunk & 15;
        float4 v = *(const float4*)(xbt + (size_t)c * 65536 + q * 4);
        xT[q * 4 + 0][c] = f2bf(v.x);
        xT[q * 4 + 1][c] = f2bf(v.y);
        xT[q * 4 + 2][c] = f2bf(v.z);
        xT[q * 4 + 3][c] = f2bf(v.w);
    }
    __syncthreads();

    // conv: y[o][f] = sum_c w[o][c] x[c][f] ; 6x4 tiles of 16x16, K=64
#pragma unroll
    for (int i = 0; i < 6; i++) {
        int tile = w * 6 + i;
        int mt = tile >> 2, nt = tile & 3;
        f32x4 acc = {0.f, 0.f, 0.f, 0.f};
#pragma unroll
        for (int kt = 0; kt < 2; kt++) {
            short8 a  = *(const short8*)(&wsb[mt * 16 + (lane & 15)][kt * 32 + (lane >> 4) * 8]);
            short8 bf = *(const short8*)(&xT [nt * 16 + (lane & 15)][kt * 32 + (lane >> 4) * 8]);
            acc = mfma_bf16(a, bf, acc);
        }
        int colf = nt * 16 + (lane & 15);
#pragma unroll
        for (int j = 0; j < 4; j++) {
            int row = mt * 16 + (lane >> 4) * 4 + j;
            float y = acc[j] + bias_s[row];
            float sl = slope_s[row];
            y = (y > 0.f) ? y : sl * y;
            ys[row][colf] = y;
        }
    }
    __syncthreads();

    // per-head LN; wave w == head h=w
    const int h = w;
    { // Q: rows 4h..4h+3, norm over 256
        float v0[4]; float s = 0.f, ss = 0.f;
#pragma unroll
        for (int o = 0; o < 4; o++) { float y = ys[h * 4 + o][lane]; v0[o] = y; s += y; ss += y * y; }
#pragma unroll
        for (int m = 1; m < 64; m <<= 1) { s += __shfl_xor(s, m, 64); ss += __shfl_xor(ss, m, 64); }
        float mu = s * (1.f / 256.f), var = ss * (1.f / 256.f) - mu * mu;
        float rs = rsqrtf(var + EPSV);
        size_t base = ((size_t)(h * 8 + b) * 1024 + t) * 256;
#pragma unroll
        for (int o = 0; o < 4; o++) {
            float val = (v0[o] - mu) * rs * qg[(h * 4 + o) * 64 + lane] + qbt[(h * 4 + o) * 64 + lane];
            Qb[base + o * 64 + lane] = f2bf(val);
        }
    }
    { // K: rows 16+4h..
        float v0[4]; float s = 0.f, ss = 0.f;
#pragma unroll
        for (int o = 0; o < 4; o++) { float y = ys[16 + h * 4 + o][lane]; v0[o] = y; s += y; ss += y * y; }
#pragma unroll
        for (int m = 1; m < 64; m <<= 1) { s += __shfl_xor(s, m, 64); ss += __shfl_xor(ss, m, 64); }
        float mu = s * (1.f / 256.f), var = ss * (1.f / 256.f) - mu * mu;
        float rs = rsqrtf(var + EPSV);
        size_t base = ((size_t)(h * 8 + b) * 1024 + t) * 256;
#pragma unroll
        for (int o = 0; o < 4; o++) {
            float val = (v0[o] - mu) * rs * kg[(h * 4 + o) * 64 + lane] + kbt[(h * 4 + o) * 64 + lane];
            Kb[base + o * 64 + lane] = f2bf(val);
        }
    }
    { // V: rows 32+16h..+15, norm over 1024
        float v0[16]; float s = 0.f, ss = 0.f;
#pragma unroll
        for (int o = 0; o < 16; o++) { float y = ys[32 + h * 16 + o][lane]; v0[o] = y; s += y; ss += y * y; }
#pragma unroll
        for (int m = 1; m < 64; m <<= 1) { s += __shfl_xor(s, m, 64); ss += __shfl_xor(ss, m, 64); }
        float mu = s * (1.f / 1024.f), var = ss * (1.f / 1024.f) - mu * mu;
        float rs = rsqrtf(var + EPSV);
        size_t base = ((size_t)(h * 8 + b) * 1024 + t) * 1024;
#pragma unroll
        for (int o = 0; o < 16; o++) {
            float val = (v0[o] - mu) * rs * vg[(h * 16 + o) * 64 + lane] + vbt[(h * 16 + o) * 64 + lane];
            Vb[base + o * 64 + lane] = f2bf(val);
        }
    }
}

// ---------------------------------------------------------------------------
// Kernel 2: transpose V [n][s][d] -> Vt [n][d][s]  (64x64 tiles via LDS)
// ---------------------------------------------------------------------------
__global__ __launch_bounds__(256) void k_vtrans(const u16* __restrict__ Vb, u16* __restrict__ Vt)
{
    __shared__ u16 ts[64][72];
    const int tid = threadIdx.x;
    const int idx = blockIdx.x;               // 32 n * 16 st * 16 dt
    const int n = idx >> 8, rest = idx & 255;
    const int s0 = (rest >> 4) * 64, d0 = (rest & 15) * 64;
    const size_t nb = (size_t)n << 20;

#pragma unroll
    for (int i = 0; i < 2; i++) {
        int chunk = tid + i * 256;            // 0..511 ; 64 rows x 8 chunks of 8 u16
        int row = chunk >> 3, q = chunk & 7;
        uint4 v = *(const uint4*)(Vb + nb + (size_t)(s0 + row) * 1024 + d0 + q * 8);
        *(uint4*)(&ts[row][q * 8]) = v;
    }
    __syncthreads();
#pragma unroll
    for (int i = 0; i < 2; i++) {
        int chunk = tid + i * 256;
        int orow = chunk >> 3, q = chunk & 7; // output d-row, s-chunk
        uint4 o;
        o.x = (unsigned)ts[q * 8 + 0][orow] | ((unsigned)ts[q * 8 + 1][orow] << 16);
        o.y = (unsigned)ts[q * 8 + 2][orow] | ((unsigned)ts[q * 8 + 3][orow] << 16);
        o.z = (unsigned)ts[q * 8 + 4][orow] | ((unsigned)ts[q * 8 + 5][orow] << 16);
        o.w = (unsigned)ts[q * 8 + 6][orow] | ((unsigned)ts[q * 8 + 7][orow] << 16);
        *(uint4*)(Vt + nb + (size_t)(d0 + orow) * 1024 + s0 + q * 8) = o;
    }
}

// ---------------------------------------------------------------------------
// Kernel 3: S = Q K^T / 16, row softmax, write normalized P bf16 [n][t][s].
// One block = one n + 16 q-rows; wave w covers s in [w*256, w*256+256).
// ---------------------------------------------------------------------------
__global__ __launch_bounds__(256) void k_attn(const u16* __restrict__ Qb, const u16* __restrict__ Kb,
                                              u16* __restrict__ P)
{
    __shared__ u16 Ks[4][16 * 256];        // 32 KB: per-wave 16x256 bf16 K tile
    __shared__ float red[2][4][16];

    const int bid = blockIdx.x;
    const int n = (bid & 7) + ((bid >> 9) << 3);   // XCD swizzle: same n -> same bid%8
    const int qt = (bid >> 3) & 63;
    const int q0 = qt * 16;
    const int tid = threadIdx.x, w = tid >> 6, lane = tid & 63;
    const int grp = lane >> 4, lc = lane & 15;

    const u16* Qn = Qb + ((size_t)n << 18);
    const u16* Kn = Kb + ((size_t)n << 18);

    // Q fragments (one-time)
    short8 qf[8];
#pragma unroll
    for (int kt = 0; kt < 8; kt++)
        qf[kt] = *(const short8*)(Qn + (size_t)(q0 + lc) * 256 + kt * 32 + grp * 8);

    u16* KsW = Ks[w];
    const int l_row = lane >> 5;          // 0..1 (2 rows per 1KB staging call)
    const int l_cs = (lane & 31) * 8;     // u16 chunk offset within row

    f32x4 sacc[16];
#pragma unroll
    for (int st = 0; st < 16; st++) {
        int s0 = w * 256 + st * 16;
        // stage 16 s-rows x 256 d: LDS linear, global source pre-swizzled
#pragma unroll
        for (int c = 0; c < 8; c++) {
            int row = c * 2 + l_row;
            int col = l_cs ^ ((row & 7) << 3);
            gload_lds16(Kn + (size_t)(s0 + row) * 256 + col, KsW + c * 512);
        }
        __syncthreads();                   // drains vmcnt(0): tile visible
        f32x4 a = {0.f, 0.f, 0.f, 0.f};
#pragma unroll
        for (int kt = 0; kt < 8; kt++) {
            int off = lc * 256 + ((kt * 32 + grp * 8) ^ ((lc & 7) << 3));
            short8 kf = *(const short8*)(KsW + off);
            a = mfma_bf16(qf[kt], kf, a);
        }
        sacc[st] = a;
        __syncthreads();                   // reads done before next stage lands
    }

    // ---- softmax over the full 1024 columns (4 waves x 256 each) ----
    float mx[4] = {-1e30f, -1e30f, -1e30f, -1e30f};
#pragma unroll
    for (int st = 0; st < 16; st++)
#pragma unroll
        for (int j = 0; j < 4; j++) {
            float v = sacc[st][j] * 0.0625f;   // 1/sqrt(256)
            sacc[st][j] = v;
            mx[j] = fmaxf(mx[j], v);
        }
#pragma unroll
    for (int m = 1; m < 16; m <<= 1)
#pragma unroll
        for (int j = 0; j < 4; j++) mx[j] = fmaxf(mx[j], __shfl_xor(mx[j], m, 64));

    if (lc == 0) {
#pragma unroll
        for (int j = 0; j < 4; j++) red[0][w][grp * 4 + j] = mx[j];
    }
    __syncthreads();
    float gm[4], sm[4] = {0.f, 0.f, 0.f, 0.f};
#pragma unroll
    for (int j = 0; j < 4; j++) {
        int row = grp * 4 + j;
        gm[j] = fmaxf(fmaxf(red[0][0][row], red[0][1][row]), fmaxf(red[0][2][row], red[0][3][row]));
    }
#pragma unroll
    for (int st = 0; st < 16; st++)
#pragma unroll
        for (int j = 0; j < 4; j++) {
            float p = __expf(sacc[st][j] - gm[j]);
            sacc[st][j] = p;
            sm[j] += p;
        }
#pragma unroll
    for (int m = 1; m < 16; m <<= 1)
#pragma unroll
        for (int j = 0; j < 4; j++) sm[j] += __shfl_xor(sm[j], m, 64);
    if (lc == 0) {
#pragma unroll
        for (int j = 0; j < 4; j++) red[1][w][grp * 4 + j] = sm[j];
    }
    __syncthreads();

    u16* Pn = P + ((size_t)n << 20);
    float inv[4];
#pragma unroll
    for (int j = 0; j < 4; j++) {
        int row = grp * 4 + j;
        float tot = red[1][0][row] + red[1][1][row] + red[1][2][row] + red[1][3][row];
        inv[j] = 1.f / tot;
    }
#pragma unroll
    for (int st = 0; st < 16; st++)
#pragma unroll
        for (int j = 0; j < 4; j++) {
            Pn[(size_t)(q0 + grp * 4 + j) * 1024 + w * 256 + st * 16 + lc] = f2bf(sacc[st][j] * inv[j]);
        }
}

// ---------------------------------------------------------------------------
// Kernel 4: A = P (1024x1024) x V (1024x1024) per n.
// 256x256 tile, BK=32, 8 waves (2Mx4N), per-wave 128x64 output.
// T3-minimum single-barrier loop: STAGE(next-buf) -> ds_read+MFMA(cur) ->
// __syncthreads (full drain) -> swap. T2 bank swizzle (chunk ^= row&3) applied
// involutively on global source and ds_read. T5 setprio around MFMA cluster.
// Epilogue scatters fp32 into [B,C,T,F].
// ---------------------------------------------------------------------------
__global__ __launch_bounds__(512, 2) void k_pv(const u16* __restrict__ P, const u16* __restrict__ Vt,
                                               float* __restrict__ out)
{
    __shared__ u16 lds[2][4][128 * 32];   // [buf][seg A0,A1,B0,B1][128 rows][32 k] = 64 KB

    const int bid = blockIdx.x;
    const int n = (bid & 7) + ((bid >> 7) << 3);    // XCD-chunked: per XCD, 16-block runs share n
    const int tile = (bid >> 3) & 15;
    const int tm = tile >> 2, tn = tile & 3;
    const int tid = threadIdx.x, w = tid >> 6, lane = tid & 63;
    const int wr = w >> 2, wc = w & 3;              // wave grid 2M x 4N
    const int lc = lane & 15, grp = lane >> 4;

    const u16* Pa = P  + ((size_t)n << 20) + (size_t)tm * 256 * 1024;
    const u16* Va = Vt + ((size_t)n << 20) + (size_t)tn * 256 * 1024;

    // staging geometry: per K-step each thread stages 1 chunk (16B) per segment.
    // chunk id within seg = tid: row = tid>>2, cc = tid&3; source col pre-swizzled.
    const int srow = tid >> 2, scc = tid & 3;
    const int scol = (scc ^ (srow & 3)) * 8;        // u16 col within the 32-wide k-slab
    const int ldst = w * 512;                       // u16 offset of this wave's chunk run

    f32x4 acc[8][4];
#pragma unroll
    for (int mi = 0; mi < 8; mi++)
#pragma unroll
        for (int ni = 0; ni < 4; ni++) acc[mi][ni] = (f32x4){0.f, 0.f, 0.f, 0.f};

#define STAGE_PV(ks_, pb_)                                                        \
    {                                                                             \
        size_t k0_ = (size_t)(ks_) * 32;                                          \
        gload_lds16(Pa + (size_t)srow * 1024 + k0_ + scol,         &lds[pb_][0][ldst]); \
        gload_lds16(Pa + (size_t)(128 + srow) * 1024 + k0_ + scol, &lds[pb_][1][ldst]); \
        gload_lds16(Va + (size_t)srow * 1024 + k0_ + scol,         &lds[pb_][2][ldst]); \
        gload_lds16(Va + (size_t)(128 + srow) * 1024 + k0_ + scol, &lds[pb_][3][ldst]); \
    }

    STAGE_PV(0, 0);
    __syncthreads();

    const int rxor = (lc & 3);                       // row&3 for all frag rows
    for (int ks = 0; ks < 32; ks++) {
        int cur = ks & 1;
        if (ks < 31) STAGE_PV(ks + 1, cur ^ 1);

        const u16* As = lds[cur][wr];                // this wave's M-half
        const u16* Bs = lds[cur][2 + (wc >> 1)];     // this wave's N-half pair
        const int brow0 = (wc & 1) * 64;

        short8 af[8], bf[4];
#pragma unroll
        for (int mi = 0; mi < 8; mi++)
            af[mi] = *(const short8*)(As + (mi * 16 + lc) * 32 + ((grp ^ rxor) * 8));
#pragma unroll
        for (int ni = 0; ni < 4; ni++)
            bf[ni] = *(const short8*)(Bs + (brow0 + ni * 16 + lc) * 32 + ((grp ^ rxor) * 8));

        __builtin_amdgcn_s_setprio(1);
#pragma unroll
        for (int mi = 0; mi < 8; mi++)
#pragma unroll
            for (int ni = 0; ni < 4; ni++)
                acc[mi][ni] = mfma_bf16(af[mi], bf[ni], acc[mi][ni]);
        __builtin_amdgcn_s_setprio(0);

        __syncthreads();                             // drains vmcnt+lgkmcnt, syncs buffers
    }
#undef STAGE_PV

    const int h = n >> 3, b = n & 7;
#pragma unroll
    for (int mi = 0; mi < 8; mi++)
#pragma unroll
        for (int ni = 0; ni < 4; ni++) {
            int d = tn * 256 + wc * 64 + ni * 16 + lc;
            int c = h * 16 + (d >> 6), f = d & 63;
#pragma unroll
            for (int j = 0; j < 4; j++) {
                int trow = tm * 256 + wr * 128 + mi * 16 + grp * 4 + j;
                out[(((size_t)b * 64 + c) * 1024 + trow) * 64 + f] = acc[mi][ni][j];
            }
        }
}

// ---------------------------------------------------------------------------
// Kernel 5: final conv block (64->64) + PReLU + LN(4096) + affine + residual,
// in-place on d_out. One block per (b,t).
// ---------------------------------------------------------------------------
__global__ __launch_bounds__(256) void k_final(
    const float* __restrict__ Ain, const float* __restrict__ x,
    const float* __restrict__ lw, const float* __restrict__ lbias, const float* __restrict__ la,
    const float* __restrict__ lg, const float* __restrict__ lbt, float* __restrict__ out)
{
    __shared__ u16 AT[64][72];     // [f][c]
    __shared__ u16 lwb[64][72];    // [o][c]
    __shared__ float ys[64][64];
    __shared__ float red[8];

    const int tid = threadIdx.x, w = tid >> 6, lane = tid & 63;
    const int b = blockIdx.x >> 10, t = blockIdx.x & 1023;
    const int lc = lane & 15, grp = lane >> 4;

#pragma unroll
    for (int i = 0; i < 16; i++) {
        int idx = tid + i * 256;
        lwb[idx >> 6][idx & 63] = f2bf(lw[idx]);
    }
    const float* Abt = Ain + ((size_t)(b * 64) * 1024 + t) * 64;
#pragma unroll
    for (int k = 0; k < 4; k++) {
        int chunk = tid + k * 256;
        int c = chunk >> 4, q = chunk & 15;
        float4 v = *(const float4*)(Abt + (size_t)c * 65536 + q * 4);
        AT[q * 4 + 0][c] = f2bf(v.x);
        AT[q * 4 + 1][c] = f2bf(v.y);
        AT[q * 4 + 2][c] = f2bf(v.z);
        AT[q * 4 + 3][c] = f2bf(v.w);
    }
    __syncthreads();

    const float slope = la[0];
    float psum = 0.f, psq = 0.f;
#pragma unroll
    for (int nt = 0; nt < 4; nt++) {
        f32x4 acc = {0.f, 0.f, 0.f, 0.f};
#pragma unroll
        for (int kt = 0; kt < 2; kt++) {
            short8 a  = *(const short8*)(&lwb[w * 16 + lc][kt * 32 + grp * 8]);
            short8 bf = *(const short8*)(&AT [nt * 16 + lc][kt * 32 + grp * 8]);
            acc = mfma_bf16(a, bf, acc);
        }
#pragma unroll
        for (int j = 0; j < 4; j++) {
            int row = w * 16 + grp * 4 + j;
            float y = acc[j] + lbias[row];
            y = (y > 0.f) ? y : slope * y;
            ys[row][nt * 16 + lc] = y;
            psum += y; psq += y * y;
        }
    }
#pragma unroll
    for (int m = 1; m < 64; m <<= 1) { psum += __shfl_xor(psum, m, 64); psq += __shfl_xor(psq, m, 64); }
    if (lane == 0) { red[w] = psum; red[4 + w] = psq; }
    __syncthreads();
    float S  = red[0] + red[1] + red[2] + red[3];
    float SS = red[4] + red[5] + red[6] + red[7];
    float mu = S * (1.f / 4096.f), var = SS * (1.f / 4096.f) - mu * mu;
    float rs = rsqrtf(var + EPSV);

    for (int idx = tid; idx < 4096; idx += 256) {
        int o = idx >> 6, f = idx & 63;
        size_t gi = ((size_t)(b * 64 + o) * 1024 + t) * 64 + f;
        out[gi] = (ys[o][f] - mu) * rs * lg[idx] + lbt[idx] + x[gi];
    }
}

// ---------------------------------------------------------------------------
extern "C" void kernel_launch(void* const* d_in, const int* in_sizes, int n_in,
                              void* d_out, int out_size, void* d_ws, size_t ws_size,
                              hipStream_t stream)
{
    const float* x    = (const float*)d_in[0];
    const float* qw   = (const float*)d_in[1];
    const float* qb   = (const float*)d_in[2];
    const float* qa   = (const float*)d_in[3];
    const float* qg   = (const float*)d_in[4];
    const float* qbt  = (const float*)d_in[5];
    const float* kw   = (const float*)d_in[6];
    const float* kb   = (const float*)d_in[7];
    const float* ka   = (const float*)d_in[8];
    const float* kg   = (const float*)d_in[9];
    const float* kbt  = (const float*)d_in[10];
    const float* vw   = (const float*)d_in[11];
    const float* vb   = (const float*)d_in[12];
    const float* va   = (const float*)d_in[13];
    const float* vg   = (const float*)d_in[14];
    const float* vbt  = (const float*)d_in[15];
    const float* lw   = (const float*)d_in[16];
    const float* lb   = (const float*)d_in[17];
    const float* la   = (const float*)d_in[18];
    const float* lg   = (const float*)d_in[19];
    const float* lbt  = (const float*)d_in[20];

    float* out = (float*)d_out;

    // Scratch layout:
    //   ws[0          .. 64MB) : Vb [32][1024][1024] bf16 ; later aliased by P
    //   ws[64MB       ..128MB) : Vt [32][1024][1024] bf16
    //   d_out[0..16MB) : Qb bf16 ; d_out[16..32MB) : Kb bf16 (dead before k_pv writes)
    u16* Vb = (u16*)d_ws;
    u16* Vt = (u16*)((char*)d_ws + ((size_t)64 << 20));
    u16* P  = Vb;
    u16* Qb = (u16*)d_out;
    u16* Kb = (u16*)((char*)d_out + ((size_t)16 << 20));

    k_qkv<<<dim3(8192), dim3(256), 0, stream>>>(x, qw, qb, qa, qg, qbt,
                                                kw, kb, ka, kg, kbt,
                                                vw, vb, va, vg, vbt, Qb, Kb, Vb);
    k_vtrans<<<dim3(8192), dim3(256), 0, stream>>>(Vb, Vt);
    k_attn<<<dim3(2048), dim3(256), 0, stream>>>(Qb, Kb, P);
    k_pv<<<dim3(512), dim3(512), 0, stream>>>(P, Vt, out);
    k_final<<<dim3(8192), dim3(256), 0, stream>>>(out, x, lw, lb, la, lg, lbt, out);
}

// Round 5
// 336.891 us; speedup vs baseline: 1.3536x; 1.0020x over previous
//
#include <hip/hip_runtime.h>

typedef unsigned short u16;
typedef __attribute__((ext_vector_type(8))) short short8;
typedef __attribute__((ext_vector_type(4))) float f32x4;

#define EPSV 1e-5f

__device__ __forceinline__ u16 f2bf(float f) {
    unsigned u = __float_as_uint(f);
    u += 0x7fffu + ((u >> 16) & 1u);
    return (u16)(u >> 16);
}

__device__ __forceinline__ f32x4 mfma_bf16(short8 a, short8 b, f32x4 c) {
    return __builtin_amdgcn_mfma_f32_16x16x32_bf16(a, b, c, 0, 0, 0);
}

__device__ __forceinline__ void gload_lds16(const void* g, void* l) {
    __builtin_amdgcn_global_load_lds((const __attribute__((address_space(1))) void*)g,
                                     (__attribute__((address_space(3))) void*)l, 16, 0, 0);
}

// ---------------------------------------------------------------------------
// Prep kernels: one-time fp32 -> bf16 weight conversion (kills per-block
// re-staging: was 6144 f2bf x 8192 blocks in k_qkv alone).
// ---------------------------------------------------------------------------
__global__ __launch_bounds__(256) void k_prep_qkv(const float* __restrict__ qw,
                                                  const float* __restrict__ kw,
                                                  const float* __restrict__ vw,
                                                  u16* __restrict__ wq)
{
    const int tid = threadIdx.x;
#pragma unroll
    for (int i = 0; i < 24; i++) {
        int idx = tid + i * 256;           // 0..6143 ; row = och (0-15 Q,16-31 K,32-95 V)
        int row = idx >> 6;
        float wv = (row < 16) ? qw[idx] : ((row < 32) ? kw[idx - 1024] : vw[idx - 2048]);
        wq[idx] = f2bf(wv);
    }
}

__global__ __launch_bounds__(256) void k_prep_lw(const float* __restrict__ lw, u16* __restrict__ lwb)
{
    const int tid = threadIdx.x;
#pragma unroll
    for (int i = 0; i < 16; i++) {
        int idx = tid + i * 256;
        lwb[idx] = f2bf(lw[idx]);
    }
}

// ---------------------------------------------------------------------------
// Kernel 1: fused QKV 1x1-conv + bias + PReLU + per-head LayerNorm + affine.
// One block per (b,t). Weights read as bf16 MFMA fragments DIRECT from global
// (L1-resident, pre-converted). ys/xT padded to stride 66 (<=2-way conflicts).
// ---------------------------------------------------------------------------
__global__ __launch_bounds__(256) void k_qkv(
    const float* __restrict__ x, const u16* __restrict__ wq,
    const float* __restrict__ qb, const float* __restrict__ qa,
    const float* __restrict__ qg, const float* __restrict__ qbt,
    const float* __restrict__ kb, const float* __restrict__ ka,
    const float* __restrict__ kg, const float* __restrict__ kbt,
    const float* __restrict__ vb, const float* __restrict__ va,
    const float* __restrict__ vg, const float* __restrict__ vbt,
    u16* __restrict__ Qb, u16* __restrict__ Kb, u16* __restrict__ Vb)
{
    __shared__ u16 xT[64][66];     // [f][c] bf16 (transposed x slice)
    __shared__ float ys[96][66];   // PReLU'd conv output [och][f]
    __shared__ float bias_s[96], slope_s[96];

    const int tid = threadIdx.x, w = tid >> 6, lane = tid & 63;
    const int b = blockIdx.x >> 10, t = blockIdx.x & 1023;
    const int lc = lane & 15, grp = lane >> 4;

    if (tid < 96) {
        int row = tid; float bv, sv;
        if (row < 16)      { bv = qb[row];      sv = qa[row >> 2]; }
        else if (row < 32) { bv = kb[row - 16]; sv = ka[(row - 16) >> 2]; }
        else               { bv = vb[row - 32]; sv = va[(row - 32) >> 4]; }
        bias_s[row] = bv; slope_s[row] = sv;
    }
    // stage x[b,:,t,:] transposed -> xT[f][c]
    const float* xbt = x + ((size_t)(b * 64) * 1024 + t) * 64;
#pragma unroll
    for (int k = 0; k < 4; k++) {
        int chunk = tid + k * 256;        // 0..1023  (64 c-rows x 16 float4)
        int c = chunk >> 4, q = chunk & 15;
        float4 v = *(const float4*)(xbt + (size_t)c * 65536 + q * 4);
        xT[q * 4 + 0][c] = f2bf(v.x);
        xT[q * 4 + 1][c] = f2bf(v.y);
        xT[q * 4 + 2][c] = f2bf(v.z);
        xT[q * 4 + 3][c] = f2bf(v.w);
    }
    __syncthreads();

    // conv: y[o][f] = sum_c w[o][c] x[c][f] ; 6x4 tiles of 16x16, K=64
#pragma unroll
    for (int i = 0; i < 6; i++) {
        int tile = w * 6 + i;
        int mt = tile >> 2, nt = tile & 3;
        f32x4 acc = {0.f, 0.f, 0.f, 0.f};
#pragma unroll
        for (int kt = 0; kt < 2; kt++) {
            short8 a  = *(const short8*)(wq + (mt * 16 + lc) * 64 + kt * 32 + grp * 8);
            short8 bf = *(const short8*)(&xT[nt * 16 + lc][kt * 32 + grp * 8]);
            acc = mfma_bf16(a, bf, acc);
        }
        int colf = nt * 16 + lc;
#pragma unroll
        for (int j = 0; j < 4; j++) {
            int row = mt * 16 + grp * 4 + j;
            float y = acc[j] + bias_s[row];
            float sl = slope_s[row];
            y = (y > 0.f) ? y : sl * y;
            ys[row][colf] = y;
        }
    }
    __syncthreads();

    // per-head LN; wave w == head h=w
    const int h = w;
    { // Q: rows 4h..4h+3, norm over 256
        float v0[4]; float s = 0.f, ss = 0.f;
#pragma unroll
        for (int o = 0; o < 4; o++) { float y = ys[h * 4 + o][lane]; v0[o] = y; s += y; ss += y * y; }
#pragma unroll
        for (int m = 1; m < 64; m <<= 1) { s += __shfl_xor(s, m, 64); ss += __shfl_xor(ss, m, 64); }
        float mu = s * (1.f / 256.f), var = ss * (1.f / 256.f) - mu * mu;
        float rs = rsqrtf(var + EPSV);
        size_t base = ((size_t)(h * 8 + b) * 1024 + t) * 256;
#pragma unroll
        for (int o = 0; o < 4; o++) {
            float val = (v0[o] - mu) * rs * qg[(h * 4 + o) * 64 + lane] + qbt[(h * 4 + o) * 64 + lane];
            Qb[base + o * 64 + lane] = f2bf(val);
        }
    }
    { // K: rows 16+4h..
        float v0[4]; float s = 0.f, ss = 0.f;
#pragma unroll
        for (int o = 0; o < 4; o++) { float y = ys[16 + h * 4 + o][lane]; v0[o] = y; s += y; ss += y * y; }
#pragma unroll
        for (int m = 1; m < 64; m <<= 1) { s += __shfl_xor(s, m, 64); ss += __shfl_xor(ss, m, 64); }
        float mu = s * (1.f / 256.f), var = ss * (1.f / 256.f) - mu * mu;
        float rs = rsqrtf(var + EPSV);
        size_t base = ((size_t)(h * 8 + b) * 1024 + t) * 256;
#pragma unroll
        for (int o = 0; o < 4; o++) {
            float val = (v0[o] - mu) * rs * kg[(h * 4 + o) * 64 + lane] + kbt[(h * 4 + o) * 64 + lane];
            Kb[base + o * 64 + lane] = f2bf(val);
        }
    }
    { // V: rows 32+16h..+15, norm over 1024
        float v0[16]; float s = 0.f, ss = 0.f;
#pragma unroll
        for (int o = 0; o < 16; o++) { float y = ys[32 + h * 16 + o][lane]; v0[o] = y; s += y; ss += y * y; }
#pragma unroll
        for (int m = 1; m < 64; m <<= 1) { s += __shfl_xor(s, m, 64); ss += __shfl_xor(ss, m, 64); }
        float mu = s * (1.f / 1024.f), var = ss * (1.f / 1024.f) - mu * mu;
        float rs = rsqrtf(var + EPSV);
        size_t base = ((size_t)(h * 8 + b) * 1024 + t) * 1024;
#pragma unroll
        for (int o = 0; o < 16; o++) {
            float val = (v0[o] - mu) * rs * vg[(h * 16 + o) * 64 + lane] + vbt[(h * 16 + o) * 64 + lane];
            Vb[base + o * 64 + lane] = f2bf(val);
        }
    }
}

// ---------------------------------------------------------------------------
// Kernel 2: transpose V [n][s][d] -> Vt [n][d][s]  (64x64 tiles via LDS)
// ---------------------------------------------------------------------------
__global__ __launch_bounds__(256) void k_vtrans(const u16* __restrict__ Vb, u16* __restrict__ Vt)
{
    __shared__ u16 ts[64][72];
    const int tid = threadIdx.x;
    const int idx = blockIdx.x;               // 32 n * 16 st * 16 dt
    const int n = idx >> 8, rest = idx & 255;
    const int s0 = (rest >> 4) * 64, d0 = (rest & 15) * 64;
    const size_t nb = (size_t)n << 20;

#pragma unroll
    for (int i = 0; i < 2; i++) {
        int chunk = tid + i * 256;            // 0..511 ; 64 rows x 8 chunks of 8 u16
        int row = chunk >> 3, q = chunk & 7;
        uint4 v = *(const uint4*)(Vb + nb + (size_t)(s0 + row) * 1024 + d0 + q * 8);
        *(uint4*)(&ts[row][q * 8]) = v;
    }
    __syncthreads();
#pragma unroll
    for (int i = 0; i < 2; i++) {
        int chunk = tid + i * 256;
        int orow = chunk >> 3, q = chunk & 7; // output d-row, s-chunk
        uint4 o;
        o.x = (unsigned)ts[q * 8 + 0][orow] | ((unsigned)ts[q * 8 + 1][orow] << 16);
        o.y = (unsigned)ts[q * 8 + 2][orow] | ((unsigned)ts[q * 8 + 3][orow] << 16);
        o.z = (unsigned)ts[q * 8 + 4][orow] | ((unsigned)ts[q * 8 + 5][orow] << 16);
        o.w = (unsigned)ts[q * 8 + 6][orow] | ((unsigned)ts[q * 8 + 7][orow] << 16);
        *(uint4*)(Vt + nb + (size_t)(d0 + orow) * 1024 + s0 + q * 8) = o;
    }
}

// ---------------------------------------------------------------------------
// Kernel 3: S = Q K^T / 16, row softmax, write normalized P bf16 [n][t][s].
// ---------------------------------------------------------------------------
__global__ __launch_bounds__(256) void k_attn(const u16* __restrict__ Qb, const u16* __restrict__ Kb,
                                              u16* __restrict__ P)
{
    __shared__ u16 Ks[4][16 * 256];        // 32 KB: per-wave 16x256 bf16 K tile
    __shared__ float red[2][4][16];

    const int bid = blockIdx.x;
    const int n = (bid & 7) + ((bid >> 9) << 3);   // XCD swizzle: same n -> same bid%8
    const int qt = (bid >> 3) & 63;
    const int q0 = qt * 16;
    const int tid = threadIdx.x, w = tid >> 6, lane = tid & 63;
    const int grp = lane >> 4, lc = lane & 15;

    const u16* Qn = Qb + ((size_t)n << 18);
    const u16* Kn = Kb + ((size_t)n << 18);

    short8 qf[8];
#pragma unroll
    for (int kt = 0; kt < 8; kt++)
        qf[kt] = *(const short8*)(Qn + (size_t)(q0 + lc) * 256 + kt * 32 + grp * 8);

    u16* KsW = Ks[w];
    const int l_row = lane >> 5;          // 0..1 (2 rows per 1KB staging call)
    const int l_cs = (lane & 31) * 8;     // u16 chunk offset within row

    f32x4 sacc[16];
#pragma unroll
    for (int st = 0; st < 16; st++) {
        int s0 = w * 256 + st * 16;
#pragma unroll
        for (int c = 0; c < 8; c++) {
            int row = c * 2 + l_row;
            int col = l_cs ^ ((row & 7) << 3);
            gload_lds16(Kn + (size_t)(s0 + row) * 256 + col, KsW + c * 512);
        }
        __syncthreads();                   // drains vmcnt(0): tile visible
        f32x4 a = {0.f, 0.f, 0.f, 0.f};
#pragma unroll
        for (int kt = 0; kt < 8; kt++) {
            int off = lc * 256 + ((kt * 32 + grp * 8) ^ ((lc & 7) << 3));
            short8 kf = *(const short8*)(KsW + off);
            a = mfma_bf16(qf[kt], kf, a);
        }
        sacc[st] = a;
        __syncthreads();                   // reads done before next stage lands
    }

    float mx[4] = {-1e30f, -1e30f, -1e30f, -1e30f};
#pragma unroll
    for (int st = 0; st < 16; st++)
#pragma unroll
        for (int j = 0; j < 4; j++) {
            float v = sacc[st][j] * 0.0625f;   // 1/sqrt(256)
            sacc[st][j] = v;
            mx[j] = fmaxf(mx[j], v);
        }
#pragma unroll
    for (int m = 1; m < 16; m <<= 1)
#pragma unroll
        for (int j = 0; j < 4; j++) mx[j] = fmaxf(mx[j], __shfl_xor(mx[j], m, 64));

    if (lc == 0) {
#pragma unroll
        for (int j = 0; j < 4; j++) red[0][w][grp * 4 + j] = mx[j];
    }
    __syncthreads();
    float gm[4], sm[4] = {0.f, 0.f, 0.f, 0.f};
#pragma unroll
    for (int j = 0; j < 4; j++) {
        int row = grp * 4 + j;
        gm[j] = fmaxf(fmaxf(red[0][0][row], red[0][1][row]), fmaxf(red[0][2][row], red[0][3][row]));
    }
#pragma unroll
    for (int st = 0; st < 16; st++)
#pragma unroll
        for (int j = 0; j < 4; j++) {
            float p = __expf(sacc[st][j] - gm[j]);
            sacc[st][j] = p;
            sm[j] += p;
        }
#pragma unroll
    for (int m = 1; m < 16; m <<= 1)
#pragma unroll
        for (int j = 0; j < 4; j++) sm[j] += __shfl_xor(sm[j], m, 64);
    if (lc == 0) {
#pragma unroll
        for (int j = 0; j < 4; j++) red[1][w][grp * 4 + j] = sm[j];
    }
    __syncthreads();

    u16* Pn = P + ((size_t)n << 20);
    float inv[4];
#pragma unroll
    for (int j = 0; j < 4; j++) {
        int row = grp * 4 + j;
        float tot = red[1][0][row] + red[1][1][row] + red[1][2][row] + red[1][3][row];
        inv[j] = 1.f / tot;
    }
#pragma unroll
    for (int st = 0; st < 16; st++)
#pragma unroll
        for (int j = 0; j < 4; j++) {
            Pn[(size_t)(q0 + grp * 4 + j) * 1024 + w * 256 + st * 16 + lc] = f2bf(sacc[st][j] * inv[j]);
        }
}

// ---------------------------------------------------------------------------
// Kernel 4: A = P x V per n. 256x256 tile, BK=32, 8 waves (2Mx4N),
// single-barrier double-buffered global_load_lds staging, T2 swizzle, T5.
// ---------------------------------------------------------------------------
__global__ __launch_bounds__(512, 2) void k_pv(const u16* __restrict__ P, const u16* __restrict__ Vt,
                                               float* __restrict__ out)
{
    __shared__ u16 lds[2][4][128 * 32];   // [buf][seg A0,A1,B0,B1][128 rows][32 k] = 64 KB

    const int bid = blockIdx.x;
    const int n = (bid & 7) + ((bid >> 7) << 3);
    const int tile = (bid >> 3) & 15;
    const int tm = tile >> 2, tn = tile & 3;
    const int tid = threadIdx.x, w = tid >> 6, lane = tid & 63;
    const int wr = w >> 2, wc = w & 3;              // wave grid 2M x 4N
    const int lc = lane & 15, grp = lane >> 4;

    const u16* Pa = P  + ((size_t)n << 20) + (size_t)tm * 256 * 1024;
    const u16* Va = Vt + ((size_t)n << 20) + (size_t)tn * 256 * 1024;

    const int srow = tid >> 2, scc = tid & 3;
    const int scol = (scc ^ (srow & 3)) * 8;
    const int ldst = w * 512;

    f32x4 acc[8][4];
#pragma unroll
    for (int mi = 0; mi < 8; mi++)
#pragma unroll
        for (int ni = 0; ni < 4; ni++) acc[mi][ni] = (f32x4){0.f, 0.f, 0.f, 0.f};

#define STAGE_PV(ks_, pb_)                                                        \
    {                                                                             \
        size_t k0_ = (size_t)(ks_) * 32;                                          \
        gload_lds16(Pa + (size_t)srow * 1024 + k0_ + scol,         &lds[pb_][0][ldst]); \
        gload_lds16(Pa + (size_t)(128 + srow) * 1024 + k0_ + scol, &lds[pb_][1][ldst]); \
        gload_lds16(Va + (size_t)srow * 1024 + k0_ + scol,         &lds[pb_][2][ldst]); \
        gload_lds16(Va + (size_t)(128 + srow) * 1024 + k0_ + scol, &lds[pb_][3][ldst]); \
    }

    STAGE_PV(0, 0);
    __syncthreads();

    const int rxor = (lc & 3);
    for (int ks = 0; ks < 32; ks++) {
        int cur = ks & 1;
        if (ks < 31) STAGE_PV(ks + 1, cur ^ 1);

        const u16* As = lds[cur][wr];
        const u16* Bs = lds[cur][2 + (wc >> 1)];
        const int brow0 = (wc & 1) * 64;

        short8 af[8], bf[4];
#pragma unroll
        for (int mi = 0; mi < 8; mi++)
            af[mi] = *(const short8*)(As + (mi * 16 + lc) * 32 + ((grp ^ rxor) * 8));
#pragma unroll
        for (int ni = 0; ni < 4; ni++)
            bf[ni] = *(const short8*)(Bs + (brow0 + ni * 16 + lc) * 32 + ((grp ^ rxor) * 8));

        __builtin_amdgcn_s_setprio(1);
#pragma unroll
        for (int mi = 0; mi < 8; mi++)
#pragma unroll
            for (int ni = 0; ni < 4; ni++)
                acc[mi][ni] = mfma_bf16(af[mi], bf[ni], acc[mi][ni]);
        __builtin_amdgcn_s_setprio(0);

        __syncthreads();
    }
#undef STAGE_PV

    const int h = n >> 3, b = n & 7;
#pragma unroll
    for (int mi = 0; mi < 8; mi++)
#pragma unroll
        for (int ni = 0; ni < 4; ni++) {
            int d = tn * 256 + wc * 64 + ni * 16 + lc;
            int c = h * 16 + (d >> 6), f = d & 63;
#pragma unroll
            for (int j = 0; j < 4; j++) {
                int trow = tm * 256 + wr * 128 + mi * 16 + grp * 4 + j;
                out[(((size_t)b * 64 + c) * 1024 + trow) * 64 + f] = acc[mi][ni][j];
            }
        }
}

// ---------------------------------------------------------------------------
// Kernel 5: final conv block (64->64) + PReLU + LN(4096) + affine + residual,
// in-place on d_out. Weights bf16 direct from global; padded LDS.
// ---------------------------------------------------------------------------
__global__ __launch_bounds__(256) void k_final(
    const float* __restrict__ Ain, const float* __restrict__ x,
    const u16* __restrict__ lwbf, const float* __restrict__ lbias, const float* __restrict__ la,
    const float* __restrict__ lg, const float* __restrict__ lbt, float* __restrict__ out)
{
    __shared__ u16 AT[64][66];     // [f][c]
    __shared__ float ys[64][66];
    __shared__ float red[8];

    const int tid = threadIdx.x, w = tid >> 6, lane = tid & 63;
    const int b = blockIdx.x >> 10, t = blockIdx.x & 1023;
    const int lc = lane & 15, grp = lane >> 4;

    const float* Abt = Ain + ((size_t)(b * 64) * 1024 + t) * 64;
#pragma unroll
    for (int k = 0; k < 4; k++) {
        int chunk = tid + k * 256;
        int c = chunk >> 4, q = chunk & 15;
        float4 v = *(const float4*)(Abt + (size_t)c * 65536 + q * 4);
        AT[q * 4 + 0][c] = f2bf(v.x);
        AT[q * 4 + 1][c] = f2bf(v.y);
        AT[q * 4 + 2][c] = f2bf(v.z);
        AT[q * 4 + 3][c] = f2bf(v.w);
    }
    __syncthreads();

    short8 af[2];
#pragma unroll
    for (int kt = 0; kt < 2; kt++)
        af[kt] = *(const short8*)(lwbf + (w * 16 + lc) * 64 + kt * 32 + grp * 8);

    const float slope = la[0];
    float psum = 0.f, psq = 0.f;
#pragma unroll
    for (int nt = 0; nt < 4; nt++) {
        f32x4 acc = {0.f, 0.f, 0.f, 0.f};
#pragma unroll
        for (int kt = 0; kt < 2; kt++) {
            short8 bf = *(const short8*)(&AT[nt * 16 + lc][kt * 32 + grp * 8]);
            acc = mfma_bf16(af[kt], bf, acc);
        }
#pragma unroll
        for (int j = 0; j < 4; j++) {
            int row = w * 16 + grp * 4 + j;
            float y = acc[j] + lbias[row];
            y = (y > 0.f) ? y : slope * y;
            ys[row][nt * 16 + lc] = y;
            psum += y; psq += y * y;
        }
    }
#pragma unroll
    for (int m = 1; m < 64; m <<= 1) { psum += __shfl_xor(psum, m, 64); psq += __shfl_xor(psq, m, 64); }
    if (lane == 0) { red[w] = psum; red[4 + w] = psq; }
    __syncthreads();
    float S  = red[0] + red[1] + red[2] + red[3];
    float SS = red[4] + red[5] + red[6] + red[7];
    float mu = S * (1.f / 4096.f), var = SS * (1.f / 4096.f) - mu * mu;
    float rs = rsqrtf(var + EPSV);

    for (int idx = tid; idx < 4096; idx += 256) {
        int o = idx >> 6, f = idx & 63;
        size_t gi = ((size_t)(b * 64 + o) * 1024 + t) * 64 + f;
        out[gi] = (ys[o][f] - mu) * rs * lg[idx] + lbt[idx] + x[gi];
    }
}

// ---------------------------------------------------------------------------
extern "C" void kernel_launch(void* const* d_in, const int* in_sizes, int n_in,
                              void* d_out, int out_size, void* d_ws, size_t ws_size,
                              hipStream_t stream)
{
    const float* x    = (const float*)d_in[0];
    const float* qw   = (const float*)d_in[1];
    const float* qb   = (const float*)d_in[2];
    const float* qa   = (const float*)d_in[3];
    const float* qg   = (const float*)d_in[4];
    const float* qbt  = (const float*)d_in[5];
    const float* kw   = (const float*)d_in[6];
    const float* kb   = (const float*)d_in[7];
    const float* ka   = (const float*)d_in[8];
    const float* kg   = (const float*)d_in[9];
    const float* kbt  = (const float*)d_in[10];
    const float* vw   = (const float*)d_in[11];
    const float* vb   = (const float*)d_in[12];
    const float* va   = (const float*)d_in[13];
    const float* vg   = (const float*)d_in[14];
    const float* vbt  = (const float*)d_in[15];
    const float* lw   = (const float*)d_in[16];
    const float* lb   = (const float*)d_in[17];
    const float* la   = (const float*)d_in[18];
    const float* lg   = (const float*)d_in[19];
    const float* lbt  = (const float*)d_in[20];

    float* out = (float*)d_out;

    // Scratch layout:
    //   ws[0   ..64MB) : Vb bf16 ; later aliased by P ; (lwbf fallback at [0,8KB) after k_pv)
    //   ws[64MB..128MB): Vt bf16 ; first 12KB transiently hold wqkv (k_prep1 -> k_qkv, then
    //                    clobbered by k_vtrans)
    //   d_out[0..16MB) : Qb bf16 ; d_out[16..32MB) : Kb bf16 (dead before k_pv writes)
    u16* Vb = (u16*)d_ws;
    u16* Vt = (u16*)((char*)d_ws + ((size_t)64 << 20));
    u16* P  = Vb;
    u16* Qb = (u16*)d_out;
    u16* Kb = (u16*)((char*)d_out + ((size_t)16 << 20));
    u16* wqkv = Vt;                        // 12 KB, valid only between k_prep_qkv and k_vtrans

    const size_t need = ((size_t)128 << 20) + 65536;
    bool early = ws_size >= need;
    u16* lwbf = early ? (u16*)((char*)d_ws + ((ws_size - 8192) & ~(size_t)255))
                      : (u16*)d_ws;        // fallback: P region, written after k_pv

    k_prep_qkv<<<dim3(1), dim3(256), 0, stream>>>(qw, kw, vw, wqkv);
    if (early) k_prep_lw<<<dim3(1), dim3(256), 0, stream>>>(lw, lwbf);
    k_qkv<<<dim3(8192), dim3(256), 0, stream>>>(x, wqkv, qb, qa, qg, qbt,
                                                kb, ka, kg, kbt,
                                                vb, va, vg, vbt, Qb, Kb, Vb);
    k_vtrans<<<dim3(8192), dim3(256), 0, stream>>>(Vb, Vt);
    k_attn<<<dim3(2048), dim3(256), 0, stream>>>(Qb, Kb, P);
    k_pv<<<dim3(512), dim3(512), 0, stream>>>(P, Vt, out);
    if (!early) k_prep_lw<<<dim3(1), dim3(256), 0, stream>>>(lw, lwbf);
    k_final<<<dim3(8192), dim3(256), 0, stream>>>(out, x, lwbf, lb, la, lg, lbt, out);
}

// Round 7
// 324.137 us; speedup vs baseline: 1.4068x; 1.0393x over previous
//
#include <hip/hip_runtime.h>

typedef unsigned short u16;
typedef unsigned int u32;
typedef __attribute__((ext_vector_type(8))) short short8;
typedef __attribute__((ext_vector_type(4))) float f32x4;

#define EPSV 1e-5f

__device__ __forceinline__ u16 f2bf(float f) {
    unsigned u = __float_as_uint(f);
    u += 0x7fffu + ((u >> 16) & 1u);
    return (u16)(u >> 16);
}

__device__ __forceinline__ f32x4 mfma_bf16(short8 a, short8 b, f32x4 c) {
    return __builtin_amdgcn_mfma_f32_16x16x32_bf16(a, b, c, 0, 0, 0);
}

__device__ __forceinline__ void gload_lds16(const void* g, void* l) {
    __builtin_amdgcn_global_load_lds((const __attribute__((address_space(1))) void*)g,
                                     (__attribute__((address_space(3))) void*)l, 16, 0, 0);
}

__device__ __forceinline__ u32 packgb(float g, float bt) {
    return (u32)f2bf(g) | ((u32)f2bf(bt) << 16);
}

// ---------------------------------------------------------------------------
// Prep 1: QKV weights bf16 [96][64] + packed gamma/beta u32 [96][64] (bf16|bf16)
// ---------------------------------------------------------------------------
__global__ __launch_bounds__(256) void k_prep_qkv(
    const float* __restrict__ qw, const float* __restrict__ kw, const float* __restrict__ vw,
    const float* __restrict__ qg, const float* __restrict__ qbt,
    const float* __restrict__ kg, const float* __restrict__ kbt,
    const float* __restrict__ vg, const float* __restrict__ vbt,
    u16* __restrict__ wq, u32* __restrict__ qgb)
{
    const int tid = threadIdx.x;
#pragma unroll
    for (int i = 0; i < 24; i++) {
        int idx = tid + i * 256;           // 0..6143 ; row = och (0-15 Q,16-31 K,32-95 V)
        int row = idx >> 6;
        float wv = (row < 16) ? qw[idx] : ((row < 32) ? kw[idx - 1024] : vw[idx - 2048]);
        wq[idx] = f2bf(wv);
    }
#pragma unroll
    for (int i = 0; i < 24; i++) {
        int idx = tid + i * 256;
        int row = idx >> 6;
        float g, bt;
        if (row < 16)      { g = qg[idx];        bt = qbt[idx]; }
        else if (row < 32) { g = kg[idx - 1024]; bt = kbt[idx - 1024]; }
        else               { g = vg[idx - 2048]; bt = vbt[idx - 2048]; }
        qgb[idx] = packgb(g, bt);
    }
}

// ---------------------------------------------------------------------------
// Prep 2 (after k_pv, into dead P region): lw bf16 [64][64] + packed lg/lbt u32
// ---------------------------------------------------------------------------
__global__ __launch_bounds__(256) void k_prep_l(
    const float* __restrict__ lw, const float* __restrict__ lg, const float* __restrict__ lbt,
    u16* __restrict__ lwb, u32* __restrict__ lgb)
{
    const int tid = threadIdx.x;
#pragma unroll
    for (int i = 0; i < 16; i++) {
        int idx = tid + i * 256;
        lwb[idx] = f2bf(lw[idx]);
        lgb[idx] = packgb(lg[idx], lbt[idx]);
    }
}

// ---------------------------------------------------------------------------
// Kernel 1: fused QKV conv + bias + PReLU + per-head LN + affine.
// One block = (b, 4 t's); wave w owns t = t0+w. LN fully in registers
// (Q/K: 16-lane reduce within grp=head; V: full-wave reduce per head).
// ---------------------------------------------------------------------------
__global__ __launch_bounds__(256, 2) void k_qkv(
    const float* __restrict__ x, const u16* __restrict__ wq, const u32* __restrict__ qgb,
    const float* __restrict__ qb, const float* __restrict__ qa,
    const float* __restrict__ kb, const float* __restrict__ ka,
    const float* __restrict__ vb, const float* __restrict__ va,
    u16* __restrict__ Qb, u16* __restrict__ Kb, u16* __restrict__ Vb)
{
    __shared__ u16 xT[256][66];     // [n = tl*64+f][c] bf16
    __shared__ u32 gb_s[96][66];    // packed (g,beta) per [och][f]
    __shared__ float bias_s[96], slope_s[96];

    const int tid = threadIdx.x, w = tid >> 6, lane = tid & 63;
    const int b = blockIdx.x >> 8, tb = blockIdx.x & 255;   // 8 b x 256 tb
    const int t0 = tb * 4, t = t0 + w;
    const int lc = lane & 15, grp = lane >> 4;

    if (tid < 96) {
        int row = tid; float bv, sv;
        if (row < 16)      { bv = qb[row];      sv = qa[row >> 2]; }
        else if (row < 32) { bv = kb[row - 16]; sv = ka[(row - 16) >> 2]; }
        else               { bv = vb[row - 32]; sv = va[(row - 32) >> 4]; }
        bias_s[row] = bv; slope_s[row] = sv;
    }
    // stage packed gamma/beta
#pragma unroll
    for (int i = 0; i < 24; i++) {
        int idx = tid + i * 256;
        gb_s[idx >> 6][idx & 63] = qgb[idx];
    }
    // stage x[b,:,t0:t0+4,:] transposed -> xT[n][c]
#pragma unroll
    for (int k = 0; k < 16; k++) {
        int idx = k * 256 + tid;          // (tl, c, q)
        int q = idx & 15, c = (idx >> 4) & 63, tl = idx >> 10;
        float4 v = *(const float4*)(x + ((size_t)(b * 64 + c) * 1024 + t0 + tl) * 64 + q * 4);
        int n = tl * 64 + q * 4;
        xT[n + 0][c] = f2bf(v.x);
        xT[n + 1][c] = f2bf(v.y);
        xT[n + 2][c] = f2bf(v.z);
        xT[n + 3][c] = f2bf(v.w);
    }
    __syncthreads();

    // conv: y[o][n] = sum_c w[o][c] x^T[n][c] ; per wave: 6 mt x 4 nt, K=64
    short8 bfr[4][2];
#pragma unroll
    for (int nt = 0; nt < 4; nt++)
#pragma unroll
        for (int kt = 0; kt < 2; kt++)
            bfr[nt][kt] = *(const short8*)(&xT[w * 64 + nt * 16 + lc][kt * 32 + grp * 8]);

    f32x4 acc[6][4];
#pragma unroll
    for (int mt = 0; mt < 6; mt++) {
        short8 af[2];
#pragma unroll
        for (int kt = 0; kt < 2; kt++)
            af[kt] = *(const short8*)(wq + (mt * 16 + lc) * 64 + kt * 32 + grp * 8);
#pragma unroll
        for (int nt = 0; nt < 4; nt++) {
            f32x4 a = {0.f, 0.f, 0.f, 0.f};
            a = mfma_bf16(af[0], bfr[nt][0], a);
            a = mfma_bf16(af[1], bfr[nt][1], a);
            acc[mt][nt] = a;
        }
    }

    // bias + PReLU (in regs)
#pragma unroll
    for (int mt = 0; mt < 6; mt++)
#pragma unroll
        for (int nt = 0; nt < 4; nt++)
#pragma unroll
            for (int j = 0; j < 4; j++) {
                int row = mt * 16 + grp * 4 + j;
                float y = acc[mt][nt][j] + bias_s[row];
                acc[mt][nt][j] = (y > 0.f) ? y : slope_s[row] * y;
            }

    // ---- Q LN (head = grp, 256 elems) ----
    {
        float s = 0.f, ss = 0.f;
#pragma unroll
        for (int nt = 0; nt < 4; nt++)
#pragma unroll
            for (int j = 0; j < 4; j++) { float y = acc[0][nt][j]; s += y; ss += y * y; }
#pragma unroll
        for (int m = 1; m < 16; m <<= 1) { s += __shfl_xor(s, m, 64); ss += __shfl_xor(ss, m, 64); }
        float mu = s * (1.f / 256.f), var = ss * (1.f / 256.f) - mu * mu;
        float rs = rsqrtf(var + EPSV);
        size_t base = ((size_t)(grp * 8 + b) * 1024 + t) * 256;
#pragma unroll
        for (int nt = 0; nt < 4; nt++)
#pragma unroll
            for (int j = 0; j < 4; j++) {
                u32 p = gb_s[grp * 4 + j][nt * 16 + lc];
                float g = __uint_as_float(p << 16), bt = __uint_as_float(p & 0xffff0000u);
                Qb[base + j * 64 + nt * 16 + lc] = f2bf((acc[0][nt][j] - mu) * rs * g + bt);
            }
    }
    // ---- K LN ----
    {
        float s = 0.f, ss = 0.f;
#pragma unroll
        for (int nt = 0; nt < 4; nt++)
#pragma unroll
            for (int j = 0; j < 4; j++) { float y = acc[1][nt][j]; s += y; ss += y * y; }
#pragma unroll
        for (int m = 1; m < 16; m <<= 1) { s += __shfl_xor(s, m, 64); ss += __shfl_xor(ss, m, 64); }
        float mu = s * (1.f / 256.f), var = ss * (1.f / 256.f) - mu * mu;
        float rs = rsqrtf(var + EPSV);
        size_t base = ((size_t)(grp * 8 + b) * 1024 + t) * 256;
#pragma unroll
        for (int nt = 0; nt < 4; nt++)
#pragma unroll
            for (int j = 0; j < 4; j++) {
                u32 p = gb_s[16 + grp * 4 + j][nt * 16 + lc];
                float g = __uint_as_float(p << 16), bt = __uint_as_float(p & 0xffff0000u);
                Kb[base + j * 64 + nt * 16 + lc] = f2bf((acc[1][nt][j] - mu) * rs * g + bt);
            }
    }
    // ---- V LN (per head hv, 1024 elems, full-wave) ----
#pragma unroll
    for (int hv = 0; hv < 4; hv++) {
        float s = 0.f, ss = 0.f;
#pragma unroll
        for (int nt = 0; nt < 4; nt++)
#pragma unroll
            for (int j = 0; j < 4; j++) { float y = acc[2 + hv][nt][j]; s += y; ss += y * y; }
#pragma unroll
        for (int m = 1; m < 64; m <<= 1) { s += __shfl_xor(s, m, 64); ss += __shfl_xor(ss, m, 64); }
        float mu = s * (1.f / 1024.f), var = ss * (1.f / 1024.f) - mu * mu;
        float rs = rsqrtf(var + EPSV);
        size_t base = ((size_t)(hv * 8 + b) * 1024 + t) * 1024;
#pragma unroll
        for (int nt = 0; nt < 4; nt++)
#pragma unroll
            for (int j = 0; j < 4; j++) {
                u32 p = gb_s[32 + hv * 16 + grp * 4 + j][nt * 16 + lc];
                float g = __uint_as_float(p << 16), bt = __uint_as_float(p & 0xffff0000u);
                Vb[base + (grp * 4 + j) * 64 + nt * 16 + lc] =
                    f2bf((acc[2 + hv][nt][j] - mu) * rs * g + bt);
            }
    }
}

// ---------------------------------------------------------------------------
// Kernel 2: transpose V [n][s][d] -> Vt [n][d][s]  (64x64 tiles via LDS)
// ---------------------------------------------------------------------------
__global__ __launch_bounds__(256) void k_vtrans(const u16* __restrict__ Vb, u16* __restrict__ Vt)
{
    __shared__ u16 ts[64][72];
    const int tid = threadIdx.x;
    const int idx = blockIdx.x;               // 32 n * 16 st * 16 dt
    const int n = idx >> 8, rest = idx & 255;
    const int s0 = (rest >> 4) * 64, d0 = (rest & 15) * 64;
    const size_t nb = (size_t)n << 20;

#pragma unroll
    for (int i = 0; i < 2; i++) {
        int chunk = tid + i * 256;            // 0..511 ; 64 rows x 8 chunks of 8 u16
        int row = chunk >> 3, q = chunk & 7;
        uint4 v = *(const uint4*)(Vb + nb + (size_t)(s0 + row) * 1024 + d0 + q * 8);
        *(uint4*)(&ts[row][q * 8]) = v;
    }
    __syncthreads();
#pragma unroll
    for (int i = 0; i < 2; i++) {
        int chunk = tid + i * 256;
        int orow = chunk >> 3, q = chunk & 7; // output d-row, s-chunk
        uint4 o;
        o.x = (unsigned)ts[q * 8 + 0][orow] | ((unsigned)ts[q * 8 + 1][orow] << 16);
        o.y = (unsigned)ts[q * 8 + 2][orow] | ((unsigned)ts[q * 8 + 3][orow] << 16);
        o.z = (unsigned)ts[q * 8 + 4][orow] | ((unsigned)ts[q * 8 + 5][orow] << 16);
        o.w = (unsigned)ts[q * 8 + 6][orow] | ((unsigned)ts[q * 8 + 7][orow] << 16);
        *(uint4*)(Vt + nb + (size_t)(d0 + orow) * 1024 + s0 + q * 8) = o;
    }
}

// ---------------------------------------------------------------------------
// Kernel 3: S = Q K^T / 16, row softmax, write normalized P bf16 [n][t][s].
// ---------------------------------------------------------------------------
__global__ __launch_bounds__(256) void k_attn(const u16* __restrict__ Qb, const u16* __restrict__ Kb,
                                              u16* __restrict__ P)
{
    __shared__ u16 Ks[4][16 * 256];        // 32 KB: per-wave 16x256 bf16 K tile
    __shared__ float red[2][4][16];

    const int bid = blockIdx.x;
    const int n = (bid & 7) + ((bid >> 9) << 3);   // XCD swizzle
    const int qt = (bid >> 3) & 63;
    const int q0 = qt * 16;
    const int tid = threadIdx.x, w = tid >> 6, lane = tid & 63;
    const int grp = lane >> 4, lc = lane & 15;

    const u16* Qn = Qb + ((size_t)n << 18);
    const u16* Kn = Kb + ((size_t)n << 18);

    short8 qf[8];
#pragma unroll
    for (int kt = 0; kt < 8; kt++)
        qf[kt] = *(const short8*)(Qn + (size_t)(q0 + lc) * 256 + kt * 32 + grp * 8);

    u16* KsW = Ks[w];
    const int l_row = lane >> 5;
    const int l_cs = (lane & 31) * 8;

    f32x4 sacc[16];
#pragma unroll
    for (int st = 0; st < 16; st++) {
        int s0 = w * 256 + st * 16;
#pragma unroll
        for (int c = 0; c < 8; c++) {
            int row = c * 2 + l_row;
            int col = l_cs ^ ((row & 7) << 3);
            gload_lds16(Kn + (size_t)(s0 + row) * 256 + col, KsW + c * 512);
        }
        __syncthreads();
        f32x4 a = {0.f, 0.f, 0.f, 0.f};
#pragma unroll
        for (int kt = 0; kt < 8; kt++) {
            int off = lc * 256 + ((kt * 32 + grp * 8) ^ ((lc & 7) << 3));
            short8 kf = *(const short8*)(KsW + off);
            a = mfma_bf16(qf[kt], kf, a);
        }
        sacc[st] = a;
        __syncthreads();
    }

    float mx[4] = {-1e30f, -1e30f, -1e30f, -1e30f};
#pragma unroll
    for (int st = 0; st < 16; st++)
#pragma unroll
        for (int j = 0; j < 4; j++) {
            float v = sacc[st][j] * 0.0625f;
            sacc[st][j] = v;
            mx[j] = fmaxf(mx[j], v);
        }
#pragma unroll
    for (int m = 1; m < 16; m <<= 1)
#pragma unroll
        for (int j = 0; j < 4; j++) mx[j] = fmaxf(mx[j], __shfl_xor(mx[j], m, 64));

    if (lc == 0) {
#pragma unroll
        for (int j = 0; j < 4; j++) red[0][w][grp * 4 + j] = mx[j];
    }
    __syncthreads();
    float gm[4], sm[4] = {0.f, 0.f, 0.f, 0.f};
#pragma unroll
    for (int j = 0; j < 4; j++) {
        int row = grp * 4 + j;
        gm[j] = fmaxf(fmaxf(red[0][0][row], red[0][1][row]), fmaxf(red[0][2][row], red[0][3][row]));
    }
#pragma unroll
    for (int st = 0; st < 16; st++)
#pragma unroll
        for (int j = 0; j < 4; j++) {
            float p = __expf(sacc[st][j] - gm[j]);
            sacc[st][j] = p;
            sm[j] += p;
        }
#pragma unroll
    for (int m = 1; m < 16; m <<= 1)
#pragma unroll
        for (int j = 0; j < 4; j++) sm[j] += __shfl_xor(sm[j], m, 64);
    if (lc == 0) {
#pragma unroll
        for (int j = 0; j < 4; j++) red[1][w][grp * 4 + j] = sm[j];
    }
    __syncthreads();

    u16* Pn = P + ((size_t)n << 20);
    float inv[4];
#pragma unroll
    for (int j = 0; j < 4; j++) {
        int row = grp * 4 + j;
        float tot = red[1][0][row] + red[1][1][row] + red[1][2][row] + red[1][3][row];
        inv[j] = 1.f / tot;
    }
#pragma unroll
    for (int st = 0; st < 16; st++)
#pragma unroll
        for (int j = 0; j < 4; j++) {
            Pn[(size_t)(q0 + grp * 4 + j) * 1024 + w * 256 + st * 16 + lc] = f2bf(sacc[st][j] * inv[j]);
        }
}

// ---------------------------------------------------------------------------
// Kernel 4: A = P x V per n. 256x256 tile, BK=32, 8 waves (2Mx4N),
// single-barrier double-buffered global_load_lds staging, T2 swizzle, T5.
// ---------------------------------------------------------------------------
__global__ __launch_bounds__(512, 2) void k_pv(const u16* __restrict__ P, const u16* __restrict__ Vt,
                                               float* __restrict__ out)
{
    __shared__ u16 lds[2][4][128 * 32];

    const int bid = blockIdx.x;
    const int n = (bid & 7) + ((bid >> 7) << 3);
    const int tile = (bid >> 3) & 15;
    const int tm = tile >> 2, tn = tile & 3;
    const int tid = threadIdx.x, w = tid >> 6, lane = tid & 63;
    const int wr = w >> 2, wc = w & 3;
    const int lc = lane & 15, grp = lane >> 4;

    const u16* Pa = P  + ((size_t)n << 20) + (size_t)tm * 256 * 1024;
    const u16* Va = Vt + ((size_t)n << 20) + (size_t)tn * 256 * 1024;

    const int srow = tid >> 2, scc = tid & 3;
    const int scol = (scc ^ (srow & 3)) * 8;
    const int ldst = w * 512;

    f32x4 acc[8][4];
#pragma unroll
    for (int mi = 0; mi < 8; mi++)
#pragma unroll
        for (int ni = 0; ni < 4; ni++) acc[mi][ni] = (f32x4){0.f, 0.f, 0.f, 0.f};

#define STAGE_PV(ks_, pb_)                                                        \
    {                                                                             \
        size_t k0_ = (size_t)(ks_) * 32;                                          \
        gload_lds16(Pa + (size_t)srow * 1024 + k0_ + scol,         &lds[pb_][0][ldst]); \
        gload_lds16(Pa + (size_t)(128 + srow) * 1024 + k0_ + scol, &lds[pb_][1][ldst]); \
        gload_lds16(Va + (size_t)srow * 1024 + k0_ + scol,         &lds[pb_][2][ldst]); \
        gload_lds16(Va + (size_t)(128 + srow) * 1024 + k0_ + scol, &lds[pb_][3][ldst]); \
    }

    STAGE_PV(0, 0);
    __syncthreads();

    const int rxor = (lc & 3);
    for (int ks = 0; ks < 32; ks++) {
        int cur = ks & 1;
        if (ks < 31) STAGE_PV(ks + 1, cur ^ 1);

        const u16* As = lds[cur][wr];
        const u16* Bs = lds[cur][2 + (wc >> 1)];
        const int brow0 = (wc & 1) * 64;

        short8 af[8], bf[4];
#pragma unroll
        for (int mi = 0; mi < 8; mi++)
            af[mi] = *(const short8*)(As + (mi * 16 + lc) * 32 + ((grp ^ rxor) * 8));
#pragma unroll
        for (int ni = 0; ni < 4; ni++)
            bf[ni] = *(const short8*)(Bs + (brow0 + ni * 16 + lc) * 32 + ((grp ^ rxor) * 8));

        __builtin_amdgcn_s_setprio(1);
#pragma unroll
        for (int mi = 0; mi < 8; mi++)
#pragma unroll
            for (int ni = 0; ni < 4; ni++)
                acc[mi][ni] = mfma_bf16(af[mi], bf[ni], acc[mi][ni]);
        __builtin_amdgcn_s_setprio(0);

        __syncthreads();
    }
#undef STAGE_PV

    const int h = n >> 3, b = n & 7;
#pragma unroll
    for (int mi = 0; mi < 8; mi++)
#pragma unroll
        for (int ni = 0; ni < 4; ni++) {
            int d = tn * 256 + wc * 64 + ni * 16 + lc;
            int c = h * 16 + (d >> 6), f = d & 63;
#pragma unroll
            for (int j = 0; j < 4; j++) {
                int trow = tm * 256 + wr * 128 + mi * 16 + grp * 4 + j;
                out[(((size_t)b * 64 + c) * 1024 + trow) * 64 + f] = acc[mi][ni][j];
            }
        }
}

// ---------------------------------------------------------------------------
// Kernel 5: final conv block + PReLU + LN(4096) + affine + residual, in-place.
// One block = (b, 4 t's); wave w owns t = t0+w; LN fully wave-local.
// ---------------------------------------------------------------------------
__global__ __launch_bounds__(256, 2) void k_final(
    const float* __restrict__ Ain, const float* __restrict__ x,
    const u16* __restrict__ lwbf, const u32* __restrict__ lgb,
    const float* __restrict__ lbias, const float* __restrict__ la,
    float* __restrict__ out)
{
    __shared__ u16 AT[256][66];     // [n = tl*64+f][c]
    __shared__ u32 gb_s[64][66];
    __shared__ float bias_s[64];

    const int tid = threadIdx.x, w = tid >> 6, lane = tid & 63;
    const int b = blockIdx.x >> 8, tb = blockIdx.x & 255;   // 8 b x 256 tb
    const int t0 = tb * 4, t = t0 + w;
    const int lc = lane & 15, grp = lane >> 4;

    if (tid < 64) bias_s[tid] = lbias[tid];
#pragma unroll
    for (int i = 0; i < 16; i++) {
        int idx = tid + i * 256;
        gb_s[idx >> 6][idx & 63] = lgb[idx];
    }
#pragma unroll
    for (int k = 0; k < 16; k++) {
        int idx = k * 256 + tid;
        int q = idx & 15, c = (idx >> 4) & 63, tl = idx >> 10;
        float4 v = *(const float4*)(Ain + ((size_t)(b * 64 + c) * 1024 + t0 + tl) * 64 + q * 4);
        int n = tl * 64 + q * 4;
        AT[n + 0][c] = f2bf(v.x);
        AT[n + 1][c] = f2bf(v.y);
        AT[n + 2][c] = f2bf(v.z);
        AT[n + 3][c] = f2bf(v.w);
    }
    __syncthreads();

    short8 bfr[4][2];
#pragma unroll
    for (int nt = 0; nt < 4; nt++)
#pragma unroll
        for (int kt = 0; kt < 2; kt++)
            bfr[nt][kt] = *(const short8*)(&AT[w * 64 + nt * 16 + lc][kt * 32 + grp * 8]);

    f32x4 acc[4][4];
#pragma unroll
    for (int mt = 0; mt < 4; mt++) {
        short8 af[2];
#pragma unroll
        for (int kt = 0; kt < 2; kt++)
            af[kt] = *(const short8*)(lwbf + (mt * 16 + lc) * 64 + kt * 32 + grp * 8);
#pragma unroll
        for (int nt = 0; nt < 4; nt++) {
            f32x4 a = {0.f, 0.f, 0.f, 0.f};
            a = mfma_bf16(af[0], bfr[nt][0], a);
            a = mfma_bf16(af[1], bfr[nt][1], a);
            acc[mt][nt] = a;
        }
    }

    const float slope = la[0];
    float s = 0.f, ss = 0.f;
#pragma unroll
    for (int mt = 0; mt < 4; mt++)
#pragma unroll
        for (int nt = 0; nt < 4; nt++)
#pragma unroll
            for (int j = 0; j < 4; j++) {
                float y = acc[mt][nt][j] + bias_s[mt * 16 + grp * 4 + j];
                y = (y > 0.f) ? y : slope * y;
                acc[mt][nt][j] = y;
                s += y; ss += y * y;
            }
#pragma unroll
    for (int m = 1; m < 64; m <<= 1) { s += __shfl_xor(s, m, 64); ss += __shfl_xor(ss, m, 64); }
    float mu = s * (1.f / 4096.f), var = ss * (1.f / 4096.f) - mu * mu;
    float rs = rsqrtf(var + EPSV);

#pragma unroll
    for (int mt = 0; mt < 4; mt++)
#pragma unroll
        for (int nt = 0; nt < 4; nt++)
#pragma unroll
            for (int j = 0; j < 4; j++) {
                int row = mt * 16 + grp * 4 + j, f = nt * 16 + lc;
                u32 p = gb_s[row][f];
                float g = __uint_as_float(p << 16), bt = __uint_as_float(p & 0xffff0000u);
                size_t gi = ((size_t)(b * 64 + row) * 1024 + t) * 64 + f;
                out[gi] = (acc[mt][nt][j] - mu) * rs * g + bt + x[gi];
            }
}

// ---------------------------------------------------------------------------
extern "C" void kernel_launch(void* const* d_in, const int* in_sizes, int n_in,
                              void* d_out, int out_size, void* d_ws, size_t ws_size,
                              hipStream_t stream)
{
    const float* x    = (const float*)d_in[0];
    const float* qw   = (const float*)d_in[1];
    const float* qb   = (const float*)d_in[2];
    const float* qa   = (const float*)d_in[3];
    const float* qg   = (const float*)d_in[4];
    const float* qbt  = (const float*)d_in[5];
    const float* kw   = (const float*)d_in[6];
    const float* kb   = (const float*)d_in[7];
    const float* ka   = (const float*)d_in[8];
    const float* kg   = (const float*)d_in[9];
    const float* kbt  = (const float*)d_in[10];
    const float* vw   = (const float*)d_in[11];
    const float* vb   = (const float*)d_in[12];
    const float* va   = (const float*)d_in[13];
    const float* vg   = (const float*)d_in[14];
    const float* vbt  = (const float*)d_in[15];
    const float* lw   = (const float*)d_in[16];
    const float* lb   = (const float*)d_in[17];
    const float* la   = (const float*)d_in[18];
    const float* lg   = (const float*)d_in[19];
    const float* lbt  = (const float*)d_in[20];

    float* out = (float*)d_out;

    // Scratch layout:
    //   ws[0   ..64MB) : Vb bf16 ; later aliased by P ; after k_pv: lwb/lgb tables
    //   ws[64MB..128MB): Vt bf16 ; first ~41KB transiently hold wqkv+qgb (prep -> k_qkv,
    //                    then clobbered by k_vtrans)
    //   d_out[0..16MB) : Qb ; [16..32MB): Kb (dead before k_pv writes A over d_out)
    u16* Vb = (u16*)d_ws;
    u16* Vt = (u16*)((char*)d_ws + ((size_t)64 << 20));
    u16* P  = Vb;
    u16* Qb = (u16*)d_out;
    u16* Kb = (u16*)((char*)d_out + ((size_t)16 << 20));

    u16* wqkv = Vt;                             // [96][64] bf16, 12 KB
    u32* qgb  = (u32*)(Vt + 8192);              // [96][64] u32, 24 KB (byte off 16K)
    u16* lwb  = (u16*)d_ws;                     // written after k_pv (P region dead)
    u32* lgb  = (u32*)((char*)d_ws + 8192);

    k_prep_qkv<<<dim3(1), dim3(256), 0, stream>>>(qw, kw, vw, qg, qbt, kg, kbt, vg, vbt,
                                                  wqkv, qgb);
    k_qkv<<<dim3(2048), dim3(256), 0, stream>>>(x, wqkv, qgb, qb, qa, kb, ka, vb, va,
                                                Qb, Kb, Vb);
    k_vtrans<<<dim3(8192), dim3(256), 0, stream>>>(Vb, Vt);
    k_attn<<<dim3(2048), dim3(256), 0, stream>>>(Qb, Kb, P);
    k_pv<<<dim3(512), dim3(512), 0, stream>>>(P, Vt, out);
    k_prep_l<<<dim3(1), dim3(256), 0, stream>>>(lw, lg, lbt, lwb, lgb);
    k_final<<<dim3(2048), dim3(256), 0, stream>>>(out, x, lwb, lgb, lb, la, out);
}